// Round 6
// baseline (8606.568 us; speedup 1.0000x reference)
//
#include <hip/hip_runtime.h>
#include <math.h>

#define B_ 128
#define P_ 196
#define E_ 2048
#define D_ 512
#define A_ 512
#define M_ 512
#define V_ 10000
#define L_ 21
#define T_ 20

#define NBLK_ 256
#define SLOTS_WORDS (NBLK_ * 16 + 16)

typedef __attribute__((ext_vector_type(8))) short bf16x8;
typedef __attribute__((ext_vector_type(4))) float f32x4;

// ---------------------------------------------------------------------------
// order kernel: stable argsort by descending caption length (B=128)
// also zeroes the slot-barrier state for the persistent loop kernel
// ---------------------------------------------------------------------------
__global__ void order_kernel(const int* __restrict__ lens, const int* __restrict__ caps,
                             int* __restrict__ order, int* __restrict__ declen,
                             int* __restrict__ row_map, int* __restrict__ tok_rows,
                             unsigned* __restrict__ bar) {
  __shared__ int s_order[B_];
  int tid = threadIdx.x;
  for (int i = tid; i < SLOTS_WORDS; i += 256) bar[i] = 0u;
  if (tid < B_) {
    int li = lens[tid];
    int r = 0;
    for (int j = 0; j < B_; ++j) {
      int lj = lens[j];
      r += (lj > li) || (lj == li && j < tid);
    }
    s_order[r] = tid;
    declen[r] = li - 1;
  }
  __syncthreads();
  if (tid < B_) order[tid] = s_order[tid];
  for (int m = tid; m < B_ * P_; m += blockDim.x) {
    int b = m / P_, p = m - b * P_;
    row_map[m] = s_order[b] * P_ + p;
  }
  for (int i = tid; i < T_ * B_; i += blockDim.x) {
    int t = i >> 7, b = i & 127;
    tok_rows[i] = caps[s_order[b] * L_ + t];
  }
}

// ---------------------------------------------------------------------------
// mean over P of sorted encoder rows
// ---------------------------------------------------------------------------
__global__ void mean_kernel(const float* __restrict__ enc, const int* __restrict__ order,
                            float* __restrict__ mean) {
  int b = blockIdx.y;
  int e = blockIdx.x * blockDim.x + threadIdx.x;
  int ob = order[b];
  const float* base = enc + (long long)ob * P_ * E_ + e;
  float s = 0.f;
  for (int p = 0; p < P_; ++p) s += base[(long long)p * E_];
  mean[b * E_ + e] = s * (1.0f / P_);
}

// ---------------------------------------------------------------------------
// generic 32x32 fp32 transpose: in [K,N] -> out [N,K];  grid (N/32, K/32)
// ---------------------------------------------------------------------------
__global__ void transpose_kernel(const float* __restrict__ in, float* __restrict__ out,
                                 int K, int N) {
  __shared__ float tt[32][33];
  int bx = blockIdx.x * 32;  // n
  int by = blockIdx.y * 32;  // k
  int lx = threadIdx.x & 31, ly = threadIdx.x >> 5;  // ly 0..7
#pragma unroll
  for (int i = 0; i < 32; i += 8) tt[ly + i][lx] = in[(long long)(by + ly + i) * N + bx + lx];
  __syncthreads();
#pragma unroll
  for (int i = 0; i < 32; i += 8)
    out[(long long)(bx + ly + i) * K + by + lx] = tt[lx][ly + i];
}

// ---------------------------------------------------------------------------
// fp32 tiled GEMM (h0/c0 init): C = A@B + bias, B row-major [K,N]
// ---------------------------------------------------------------------------
__global__ __launch_bounds__(256) void gemm32_kernel(
    const float* __restrict__ A, const float* __restrict__ Bm,
    const float* __restrict__ bias, float* __restrict__ C, int M, int N, int K) {
  __shared__ float As[16][64];
  __shared__ float Bs[16][64];
  const int tid = threadIdx.x;
  const int bm = blockIdx.y * 64, bn = blockIdx.x * 64;
  const int tm = tid >> 4, tn = tid & 15;
  float acc[4][4];
#pragma unroll
  for (int i = 0; i < 4; ++i)
#pragma unroll
    for (int j = 0; j < 4; ++j) acc[i][j] = 0.f;
  const int lm = tid >> 2;
  const int lk = (tid & 3) * 4;
  for (int k0 = 0; k0 < K; k0 += 16) {
    {
      int m = bm + lm;
      float4 v = make_float4(0.f, 0.f, 0.f, 0.f);
      if (m < M) v = *(const float4*)(A + (long long)m * K + k0 + lk);
      As[lk + 0][lm] = v.x;
      As[lk + 1][lm] = v.y;
      As[lk + 2][lm] = v.z;
      As[lk + 3][lm] = v.w;
    }
    {
      int k = tid >> 4;
      int n4 = (tid & 15) * 4;
      int n = bn + n4;
      float4 v = make_float4(0.f, 0.f, 0.f, 0.f);
      if (n < N) v = *(const float4*)(Bm + (long long)(k0 + k) * N + n);
      Bs[k][n4 + 0] = v.x;
      Bs[k][n4 + 1] = v.y;
      Bs[k][n4 + 2] = v.z;
      Bs[k][n4 + 3] = v.w;
    }
    __syncthreads();
#pragma unroll
    for (int k = 0; k < 16; ++k) {
      float a0 = As[k][tm * 4 + 0], a1 = As[k][tm * 4 + 1];
      float a2 = As[k][tm * 4 + 2], a3 = As[k][tm * 4 + 3];
      float b0 = Bs[k][tn * 4 + 0], b1 = Bs[k][tn * 4 + 1];
      float b2 = Bs[k][tn * 4 + 2], b3 = Bs[k][tn * 4 + 3];
      acc[0][0] += a0 * b0; acc[0][1] += a0 * b1; acc[0][2] += a0 * b2; acc[0][3] += a0 * b3;
      acc[1][0] += a1 * b0; acc[1][1] += a1 * b1; acc[1][2] += a1 * b2; acc[1][3] += a1 * b3;
      acc[2][0] += a2 * b0; acc[2][1] += a2 * b1; acc[2][2] += a2 * b2; acc[2][3] += a2 * b3;
      acc[3][0] += a3 * b0; acc[3][1] += a3 * b1; acc[3][2] += a3 * b2; acc[3][3] += a3 * b3;
    }
    __syncthreads();
  }
#pragma unroll
  for (int i = 0; i < 4; ++i) {
    int m = bm + tm * 4 + i;
    if (m >= M) continue;
#pragma unroll
    for (int j = 0; j < 4; ++j) {
      int n = bn + tn * 4 + j;
      if (n >= N) continue;
      C[(long long)m * N + n] = acc[i][j] + (bias ? bias[n] : 0.f);
    }
  }
}

// ---------------------------------------------------------------------------
// bf16 split helpers
// ---------------------------------------------------------------------------
__device__ __forceinline__ unsigned f2bf_u(float f) {
  unsigned u = __float_as_uint(f);
  return (u + 0x7fffu + ((u >> 16) & 1u)) >> 16;
}

// stage 16 floats (one thread's strip, 128-row tiles): rows r, k-groups kq/8, kq/8+1
__device__ __forceinline__ void stage16(short* __restrict__ Ph, short* __restrict__ Pl,
                                        int r, int kq, float4 v0, float4 v1, float4 v2,
                                        float4 v3, bool split) {
  float f[16] = {v0.x, v0.y, v0.z, v0.w, v1.x, v1.y, v1.z, v1.w,
                 v2.x, v2.y, v2.z, v2.w, v3.x, v3.y, v3.z, v3.w};
#pragma unroll
  for (int g2 = 0; g2 < 2; ++g2) {
    int gg = (kq >> 3) + g2;
    int slot = gg ^ ((r >> 1) & 3);
    unsigned hb[8];
    float lf[8];
#pragma unroll
    for (int j = 0; j < 8; ++j) {
      float x = f[g2 * 8 + j];
      hb[j] = f2bf_u(x);
      lf[j] = x - __uint_as_float(hb[j] << 16);
    }
    int4 ph;
    ph.x = (int)(hb[0] | (hb[1] << 16));
    ph.y = (int)(hb[2] | (hb[3] << 16));
    ph.z = (int)(hb[4] | (hb[5] << 16));
    ph.w = (int)(hb[6] | (hb[7] << 16));
    *(int4*)&Ph[r * 32 + slot * 8] = ph;
    if (split) {
      unsigned lb[8];
#pragma unroll
      for (int j = 0; j < 8; ++j) lb[j] = f2bf_u(lf[j]);
      int4 pl;
      pl.x = (int)(lb[0] | (lb[1] << 16));
      pl.y = (int)(lb[2] | (lb[3] << 16));
      pl.z = (int)(lb[4] | (lb[5] << 16));
      pl.w = (int)(lb[6] | (lb[7] << 16));
      *(int4*)&Pl[r * 32 + slot * 8] = pl;
    }
  }
}

// stage 8 floats (64-row tiles): row r, k-group kq8 (0..3)
__device__ __forceinline__ void stage8(short* __restrict__ Ph, short* __restrict__ Pl,
                                       int r, int kq8, float4 v0, float4 v1) {
  int slot = kq8 ^ ((r >> 1) & 3);
  float f[8] = {v0.x, v0.y, v0.z, v0.w, v1.x, v1.y, v1.z, v1.w};
  unsigned hb[8];
  float lf[8];
#pragma unroll
  for (int j = 0; j < 8; ++j) {
    hb[j] = f2bf_u(f[j]);
    lf[j] = f[j] - __uint_as_float(hb[j] << 16);
  }
  int4 ph;
  ph.x = (int)(hb[0] | (hb[1] << 16));
  ph.y = (int)(hb[2] | (hb[3] << 16));
  ph.z = (int)(hb[4] | (hb[5] << 16));
  ph.w = (int)(hb[6] | (hb[7] << 16));
  *(int4*)&Ph[r * 32 + slot * 8] = ph;
  unsigned lb[8];
#pragma unroll
  for (int j = 0; j < 8; ++j) lb[j] = f2bf_u(lf[j]);
  int4 pl;
  pl.x = (int)(lb[0] | (lb[1] << 16));
  pl.y = (int)(lb[2] | (lb[3] << 16));
  pl.z = (int)(lb[4] | (lb[5] << 16));
  pl.w = (int)(lb[6] | (lb[7] << 16));
  *(int4*)&Pl[r * 32 + slot * 8] = pl;
}

__device__ __forceinline__ bf16x8 frag_load(const short* __restrict__ P, int row, int g) {
  int slot = g ^ ((row >> 1) & 3);
  return *(const bf16x8*)&P[row * 32 + slot * 8];
}

// ---------------------------------------------------------------------------
// big MFMA GEMM (att1 / g_emb / fc): 128x128 tile, BK=32, register prefetch.
// MODE 0: C[m*ldc+n] = acc + bias (+bias2)   MODE 1: fc masked scatter
// SWZ: group the gridDim.x blocks sharing an A-panel onto one XCD
// ---------------------------------------------------------------------------
template <int MODE, bool SPLIT, bool SWZ>
__global__ __launch_bounds__(256) void mfma_gemm(
    const float* __restrict__ A, int lda, const int* __restrict__ row_map,
    const float* __restrict__ Bn, int ldb,
    const float* __restrict__ bias, const float* __restrict__ bias2,
    float* __restrict__ C, int ldc, int M, int N, int K,
    const int* __restrict__ declen) {
  __shared__ short Ah[128 * 32];
  __shared__ short Bh[128 * 32];
  __shared__ short Al[128 * 32];
  __shared__ short Bl[128 * 32];
  const int tid = threadIdx.x;
  int bxi, byi;
  if (SWZ) {
    int gx = gridDim.x, gy = gridDim.y;
    int id = blockIdx.y * gx + blockIdx.x;
    int super = 8 * gx;
    int body = (gy & ~7) * gx;
    if (id < body) {
      int s = id / super, rem = id % super;
      byi = s * 8 + (rem & 7);
      bxi = rem >> 3;
    } else {
      int rem = id - body;
      byi = (gy & ~7) + rem / gx;
      bxi = rem % gx;
    }
  } else {
    bxi = blockIdx.x;
    byi = blockIdx.y;
  }
  const int bm = byi * 128, bn = bxi * 128;

  f32x4 acc[4][4];
#pragma unroll
  for (int i = 0; i < 4; ++i)
#pragma unroll
    for (int j = 0; j < 4; ++j) acc[i][j] = (f32x4){0.f, 0.f, 0.f, 0.f};

  const int r = tid >> 1;
  const int kq = (tid & 1) * 16;
  const int am = bm + r;
  const long long arow = row_map ? (long long)row_map[am] : (long long)am;
  const float* ap = A + arow * (long long)lda + kq;
  const int gn = bn + r;
  const float* bp = Bn + (long long)gn * ldb + kq;
  const bool bok = gn < N;

  const int lane = tid & 63;
  const int wv = tid >> 6, wr = wv >> 1, wc = wv & 1;
  const int lr = lane & 15, g = lane >> 4;

  float4 z4 = make_float4(0.f, 0.f, 0.f, 0.f);
  float4 a0 = *(const float4*)(ap), a1 = *(const float4*)(ap + 4);
  float4 a2 = *(const float4*)(ap + 8), a3 = *(const float4*)(ap + 12);
  float4 b0 = bok ? *(const float4*)(bp) : z4;
  float4 b1 = bok ? *(const float4*)(bp + 4) : z4;
  float4 b2 = bok ? *(const float4*)(bp + 8) : z4;
  float4 b3 = bok ? *(const float4*)(bp + 12) : z4;

  for (int k0 = 0; k0 < K; k0 += 32) {
    stage16(Ah, Al, r, kq, a0, a1, a2, a3, SPLIT);
    stage16(Bh, Bl, r, kq, b0, b1, b2, b3, SPLIT);
    __syncthreads();
    if (k0 + 32 < K) {
      int kn = k0 + 32;
      a0 = *(const float4*)(ap + kn);
      a1 = *(const float4*)(ap + kn + 4);
      a2 = *(const float4*)(ap + kn + 8);
      a3 = *(const float4*)(ap + kn + 12);
      b0 = bok ? *(const float4*)(bp + kn) : z4;
      b1 = bok ? *(const float4*)(bp + kn + 4) : z4;
      b2 = bok ? *(const float4*)(bp + kn + 8) : z4;
      b3 = bok ? *(const float4*)(bp + kn + 12) : z4;
    }
    bf16x8 ah[4], bh[4];
#pragma unroll
    for (int i = 0; i < 4; ++i) {
      ah[i] = frag_load(Ah, wr * 64 + i * 16 + lr, g);
      bh[i] = frag_load(Bh, wc * 64 + i * 16 + lr, g);
    }
#pragma unroll
    for (int i = 0; i < 4; ++i)
#pragma unroll
      for (int j = 0; j < 4; ++j)
        acc[i][j] = __builtin_amdgcn_mfma_f32_16x16x32_bf16(ah[i], bh[j], acc[i][j], 0, 0, 0);
    if (SPLIT) {
      bf16x8 al2[4], bl2[4];
#pragma unroll
      for (int i = 0; i < 4; ++i) {
        al2[i] = frag_load(Al, wr * 64 + i * 16 + lr, g);
        bl2[i] = frag_load(Bl, wc * 64 + i * 16 + lr, g);
      }
#pragma unroll
      for (int i = 0; i < 4; ++i)
#pragma unroll
        for (int j = 0; j < 4; ++j)
          acc[i][j] = __builtin_amdgcn_mfma_f32_16x16x32_bf16(al2[i], bh[j], acc[i][j], 0, 0, 0);
#pragma unroll
      for (int i = 0; i < 4; ++i)
#pragma unroll
        for (int j = 0; j < 4; ++j)
          acc[i][j] = __builtin_amdgcn_mfma_f32_16x16x32_bf16(ah[i], bl2[j], acc[i][j], 0, 0, 0);
    }
    __syncthreads();
  }

#pragma unroll
  for (int j = 0; j < 4; ++j) {
    int n = bn + wc * 64 + j * 16 + lr;
    float bj = 0.f;
    if (n < N) {
      if (bias) bj += bias[n];
      if (bias2) bj += bias2[n];
    }
#pragma unroll
    for (int i = 0; i < 4; ++i) {
#pragma unroll
      for (int rr = 0; rr < 4; ++rr) {
        int m = bm + wr * 64 + i * 16 + g * 4 + rr;
        float v = acc[i][j][rr] + bj;
        if (MODE == 0) {
          C[(long long)m * ldc + n] = v;
        } else {
          if (n < N) {
            int b = m & 127, t = m >> 7;
            C[(long long)b * (T_ * V_) + (long long)t * V_ + n] = (t < declen[b]) ? v : 0.f;
          }
        }
      }
    }
  }
}

// ---------------------------------------------------------------------------
// 64x64 split-bf16 MFMA tile (device helper for the persistent loop kernel)
// ---------------------------------------------------------------------------
__device__ __forceinline__ void mfma_tile64(
    const float* __restrict__ ap, const float* __restrict__ bp, int K,
    f32x4 (&acc)[2][2], short* Ah, short* Al, short* Bh, short* Bl,
    int sr, int skq, int wr, int wc, int lr, int g) {
  float4 a0 = *(const float4*)(ap), a1 = *(const float4*)(ap + 4);
  float4 b0 = *(const float4*)(bp), b1 = *(const float4*)(bp + 4);
  for (int k0 = 0; k0 < K; k0 += 32) {
    stage8(Ah, Al, sr, skq, a0, a1);
    stage8(Bh, Bl, sr, skq, b0, b1);
    __syncthreads();
    if (k0 + 32 < K) {
      a0 = *(const float4*)(ap + k0 + 32);
      a1 = *(const float4*)(ap + k0 + 36);
      b0 = *(const float4*)(bp + k0 + 32);
      b1 = *(const float4*)(bp + k0 + 36);
    }
    bf16x8 fah[2], fbh[2], fal[2], fbl[2];
#pragma unroll
    for (int i = 0; i < 2; ++i) {
      fah[i] = frag_load(Ah, wr * 32 + i * 16 + lr, g);
      fal[i] = frag_load(Al, wr * 32 + i * 16 + lr, g);
      fbh[i] = frag_load(Bh, wc * 32 + i * 16 + lr, g);
      fbl[i] = frag_load(Bl, wc * 32 + i * 16 + lr, g);
    }
#pragma unroll
    for (int i = 0; i < 2; ++i)
#pragma unroll
      for (int j = 0; j < 2; ++j) {
        acc[i][j] = __builtin_amdgcn_mfma_f32_16x16x32_bf16(fah[i], fbh[j], acc[i][j], 0, 0, 0);
        acc[i][j] = __builtin_amdgcn_mfma_f32_16x16x32_bf16(fal[i], fbh[j], acc[i][j], 0, 0, 0);
        acc[i][j] = __builtin_amdgcn_mfma_f32_16x16x32_bf16(fah[i], fbl[j], acc[i][j], 0, 0, 0);
      }
    __syncthreads();
  }
}

// ---------------------------------------------------------------------------
// slot-based software grid barrier (no RMW contention):
// block i  (i>0): release-store target into its own padded slot, spin on flag
// block 0: thread i spins on slot i (parallel detection), then releases flag
// monotonic targets; state zeroed each call by order_kernel
// ---------------------------------------------------------------------------
__device__ __forceinline__ void gsync(unsigned* __restrict__ slots,
                                      unsigned* __restrict__ flag, unsigned target) {
  __syncthreads();
  if (blockIdx.x == 0) {
    int i = threadIdx.x;
    if (i > 0 && i < NBLK_) {
      while (__hip_atomic_load(&slots[i * 16], __ATOMIC_ACQUIRE,
                               __HIP_MEMORY_SCOPE_AGENT) < target) {
        __builtin_amdgcn_s_sleep(1);
      }
    }
    __syncthreads();
    if (threadIdx.x == 0) {
      __threadfence();
      __hip_atomic_store(flag, target, __ATOMIC_RELEASE, __HIP_MEMORY_SCOPE_AGENT);
    }
  } else {
    if (threadIdx.x == 0) {
      __threadfence();
      __hip_atomic_store(&slots[blockIdx.x * 16], target, __ATOMIC_RELEASE,
                         __HIP_MEMORY_SCOPE_AGENT);
      while (__hip_atomic_load(flag, __ATOMIC_ACQUIRE, __HIP_MEMORY_SCOPE_AGENT) < target) {
        __builtin_amdgcn_s_sleep(1);
      }
      __threadfence();
    }
  }
  __syncthreads();
}

// ---------------------------------------------------------------------------
// persistent kernel: the whole 20-step decoder loop, 256 blocks x 256 threads
// phase A: [att2 | gate | gh=h@Whh^T] split-MFMA (144 blocks, N=4608, K=512)
// phase B: e/softmax/alpha + awe*gate -> xh (2 blocks per batch row)
// phase C: g2 = xh @ Wih[:,512:]^T, 4-way split-K split-MFMA (256 blocks)
// phase D: LSTM elementwise -> c, h_all[t+1]
// ---------------------------------------------------------------------------
__global__ __launch_bounds__(256, 1) void loop_kernel(
    const float* __restrict__ att1, const float* __restrict__ enc,
    const int* __restrict__ order, const int* __restrict__ declen,
    const float* __restrict__ decT, const float* __restrict__ decb,
    const float* __restrict__ fbT, const float* __restrict__ fbb,
    const float* __restrict__ whh, const float* __restrict__ wih,
    const float* __restrict__ faw, const float* __restrict__ fab,
    const float* __restrict__ g_all, float* __restrict__ g_part,
    float* __restrict__ gh, float* __restrict__ h_all, float* __restrict__ c,
    float* __restrict__ xh, float* __restrict__ gate, float* __restrict__ att2,
    float* __restrict__ alphas_out, unsigned* __restrict__ bar) {
  __shared__ short Ah[64 * 32];
  __shared__ short Bh[64 * 32];
  __shared__ short Al[64 * 32];
  __shared__ short Bl[64 * 32];
  __shared__ float att2_s[512];
  __shared__ float w_s[512];
  __shared__ float e_s[P_];
  __shared__ float red[8];

  unsigned* slots = bar;
  unsigned* flag = bar + NBLK_ * 16;
  unsigned tgt = 0;

  const int bid = blockIdx.x, tid = threadIdx.x;
  const int lane = tid & 63, wv = tid >> 6, wr = wv >> 1, wc = wv & 1;
  const int lr = lane & 15, g = lane >> 4;
  const int sr = tid >> 2, skq = tid & 3;

  for (int t = 0; t < T_; ++t) {
    const float* h_cur = h_all + t * (B_ * D_);
    // ---------------- phase A ----------------
    if (bid < 144) {
      int nt = bid % 72, mt = bid / 72;
      int bn = nt * 64;
      const float* Bb;
      if (bn < 512) Bb = decT + bn * 512;
      else if (bn < 2560) Bb = fbT + (bn - 512) * 512;
      else Bb = whh + (bn - 2560) * 512;
      f32x4 acc[2][2];
#pragma unroll
      for (int i = 0; i < 2; ++i)
#pragma unroll
        for (int j = 0; j < 2; ++j) acc[i][j] = (f32x4){0.f, 0.f, 0.f, 0.f};
      mfma_tile64(h_cur + (mt * 64 + sr) * 512 + skq * 8, Bb + sr * 512 + skq * 8, 512,
                  acc, Ah, Al, Bh, Bl, sr, skq, wr, wc, lr, g);
#pragma unroll
      for (int j = 0; j < 2; ++j) {
        int n = bn + wc * 32 + j * 16 + lr;
#pragma unroll
        for (int i = 0; i < 2; ++i) {
#pragma unroll
          for (int rr = 0; rr < 4; ++rr) {
            int m = mt * 64 + wr * 32 + i * 16 + g * 4 + rr;
            float v = acc[i][j][rr];
            if (bn < 512) {
              att2[m * 512 + n] = v + decb[n];
            } else if (bn < 2560) {
              int nc = n - 512;
              gate[m * 2048 + nc] = 1.f / (1.f + __expf(-(v + fbb[nc])));
            } else {
              gh[m * 2048 + (n - 2560)] = v;
            }
          }
        }
      }
    }
    gsync(slots, flag, ++tgt);
    // ---------------- phase B ----------------
    {
      const int b = bid & 127, half = bid >> 7;
      for (int i = tid; i < 512; i += 256) {
        att2_s[i] = att2[b * 512 + i];
        w_s[i] = faw[i];
      }
      __syncthreads();
      for (int p = wv; p < P_; p += 4) {
        const float* row = att1 + ((long long)b * P_ + p) * 512;
        float s = 0.f;
#pragma unroll
        for (int i2 = 0; i2 < 8; ++i2) {
          int ix = lane + i2 * 64;
          float v = row[ix] + att2_s[ix];
          s += (v > 0.f ? v : 0.f) * w_s[ix];
        }
        for (int off = 32; off; off >>= 1) s += __shfl_down(s, off);
        if (lane == 0) e_s[p] = s + fab[0];
      }
      __syncthreads();
      float mx = -1e30f;
      for (int p = tid; p < P_; p += 256) mx = fmaxf(mx, e_s[p]);
      for (int off = 32; off; off >>= 1) mx = fmaxf(mx, __shfl_down(mx, off));
      if (lane == 0) red[wv] = mx;
      __syncthreads();
      mx = fmaxf(fmaxf(red[0], red[1]), fmaxf(red[2], red[3]));
      float ssum = 0.f;
      for (int p = tid; p < P_; p += 256) {
        float ev = __expf(e_s[p] - mx);
        e_s[p] = ev;
        ssum += ev;
      }
      for (int off = 32; off; off >>= 1) ssum += __shfl_down(ssum, off);
      if (lane == 0) red[4 + wv] = ssum;
      __syncthreads();
      float inv = 1.f / (red[4] + red[5] + red[6] + red[7]);
      const bool active = (t < declen[b]);
      for (int p = tid; p < P_; p += 256) {
        float al = e_s[p] * inv;
        e_s[p] = al;
        if (half == 0)
          alphas_out[(long long)b * (T_ * P_) + t * P_ + p] = active ? al : 0.f;
      }
      __syncthreads();
      const int ob = order[b];
      const float* eb = enc + (long long)ob * (P_ * E_);
      for (int e0 = half * 1024 + tid; e0 < half * 1024 + 1024; e0 += 256) {
        float s2 = 0.f;
#pragma unroll 4
        for (int p = 0; p < P_; ++p) s2 += e_s[p] * eb[p * 2048 + e0];
        xh[b * 2048 + e0] = gate[b * 2048 + e0] * s2;
      }
    }
    gsync(slots, flag, ++tgt);
    // ---------------- phase C ----------------
    {
      int kc = bid >> 6, rem = bid & 63, mt = rem >> 5, nt = rem & 31;
      int bn = nt * 64;
      f32x4 acc[2][2];
#pragma unroll
      for (int i = 0; i < 2; ++i)
#pragma unroll
        for (int j = 0; j < 2; ++j) acc[i][j] = (f32x4){0.f, 0.f, 0.f, 0.f};
      mfma_tile64(xh + (mt * 64 + sr) * 2048 + kc * 512 + skq * 8,
                  wih + (long long)(bn + sr) * 2560 + 512 + kc * 512 + skq * 8, 512,
                  acc, Ah, Al, Bh, Bl, sr, skq, wr, wc, lr, g);
      float* gp = g_part + kc * (128 * 2048);
#pragma unroll
      for (int j = 0; j < 2; ++j) {
        int n = bn + wc * 32 + j * 16 + lr;
#pragma unroll
        for (int i = 0; i < 2; ++i) {
#pragma unroll
          for (int rr = 0; rr < 4; ++rr) {
            int m = mt * 64 + wr * 32 + i * 16 + g * 4 + rr;
            gp[m * 2048 + n] = acc[i][j][rr];
          }
        }
      }
    }
    gsync(slots, flag, ++tgt);
    // ---------------- phase D ----------------
    {
      int idx = bid * 256 + tid;
      int b = idx >> 9, d = idx & 511;
      int base = b * 2048 + d;
      const float* ge = g_all + (long long)t * (128 * 2048);
      float gi = ge[base] + gh[base];
      float gf2 = ge[base + 512] + gh[base + 512];
      float gg2 = ge[base + 1024] + gh[base + 1024];
      float go = ge[base + 1536] + gh[base + 1536];
#pragma unroll
      for (int kc = 0; kc < 4; ++kc) {
        const float* gp = g_part + kc * (128 * 2048) + base;
        gi += gp[0];
        gf2 += gp[512];
        gg2 += gp[1024];
        go += gp[1536];
      }
      float si = 1.f / (1.f + __expf(-gi));
      float sf = 1.f / (1.f + __expf(-gf2));
      float so = 1.f / (1.f + __expf(-go));
      float cn = sf * c[idx] + si * tanhf(gg2);
      float hn = so * tanhf(cn);
      c[idx] = cn;
      h_all[(t + 1) * (B_ * D_) + idx] = hn;
    }
    gsync(slots, flag, ++tgt);
  }
}

// ---------------------------------------------------------------------------
// launch
// ---------------------------------------------------------------------------
extern "C" void kernel_launch(void* const* d_in, const int* in_sizes, int n_in,
                              void* d_out, int out_size, void* d_ws, size_t ws_size,
                              hipStream_t stream) {
  const float* enc       = (const float*)d_in[0];
  const int*   caps      = (const int*)d_in[1];
  const int*   lens      = (const int*)d_in[2];
  const float* emb       = (const float*)d_in[3];
  const float* enc_att_w = (const float*)d_in[4];
  const float* enc_att_b = (const float*)d_in[5];
  const float* dec_att_w = (const float*)d_in[6];
  const float* dec_att_b = (const float*)d_in[7];
  const float* full_att_w = (const float*)d_in[8];
  const float* full_att_b = (const float*)d_in[9];
  const float* init_h_w  = (const float*)d_in[10];
  const float* init_h_b  = (const float*)d_in[11];
  const float* init_c_w  = (const float*)d_in[12];
  const float* init_c_b  = (const float*)d_in[13];
  const float* f_beta_w  = (const float*)d_in[14];
  const float* f_beta_b  = (const float*)d_in[15];
  const float* lstm_w_ih = (const float*)d_in[16];
  const float* lstm_b_ih = (const float*)d_in[17];
  const float* lstm_w_hh = (const float*)d_in[18];
  const float* lstm_b_hh = (const float*)d_in[19];
  const float* fc_w      = (const float*)d_in[20];
  const float* fc_b      = (const float*)d_in[21];

  float* out = (float*)d_out;
  float* alphas_out = out + (long long)B_ * T_ * V_;

  // scratch in the (dead until final fc) preds region of d_out
  float* g_all    = out;                        // 5.24M floats
  float* g_part   = out + 6 * 1024 * 1024;      // 1.05M
  float* encattwT = out + 8 * 1024 * 1024;      // 1.05M  [N=512][K=2048]
  float* decT     = out + 9 * 1024 * 1024 + 512 * 1024;  // 0.26M [512][512]
  float* fbT      = decT + 512 * 512;           // 1.05M [2048][512]
  float* gh       = out + 12 * 1024 * 1024;     // 0.26M [128][2048]

  // workspace
  float* ws = (float*)d_ws;
  float* att1  = ws;                                // 25088*512
  float* mean  = att1 + (long long)B_ * P_ * A_;    // 128*2048
  float* h_all = mean + B_ * E_;                    // 21*128*512
  float* c     = h_all + (T_ + 1) * B_ * D_;        // 128*512
  float* att2  = c + B_ * D_;                       // 128*512
  float* gate  = att2 + B_ * A_;                    // 128*2048
  float* xh    = gate + B_ * E_;                    // 128*2048
  int* order   = (int*)(xh + B_ * E_);
  int* declen  = order + B_;
  int* row_map = declen + B_;                       // 25088
  int* tok_rows = row_map + B_ * P_;                // 2560
  unsigned* bar = (unsigned*)(tok_rows + T_ * B_);  // slot barrier state

  // 1. sort + index maps + barrier reset
  hipLaunchKernelGGL(order_kernel, dim3(1), dim3(256), 0, stream, lens, caps, order, declen,
                     row_map, tok_rows, bar);
  // 2. weight transposes ([K,N] -> [N,K])
  hipLaunchKernelGGL(transpose_kernel, dim3(16, 64), dim3(256), 0, stream, enc_att_w,
                     encattwT, E_, A_);
  hipLaunchKernelGGL(transpose_kernel, dim3(16, 16), dim3(256), 0, stream, dec_att_w, decT,
                     D_, A_);
  hipLaunchKernelGGL(transpose_kernel, dim3(64, 16), dim3(256), 0, stream, f_beta_w, fbT,
                     D_, E_);
  // 3. mean
  hipLaunchKernelGGL(mean_kernel, dim3(E_ / 256, B_), dim3(256), 0, stream, enc, order, mean);
  // 4/5. h0, c0 (fp32)
  hipLaunchKernelGGL(gemm32_kernel, dim3(D_ / 64, 2), dim3(256), 0, stream, mean, init_h_w,
                     init_h_b, h_all, B_, D_, E_);
  hipLaunchKernelGGL(gemm32_kernel, dim3(D_ / 64, 2), dim3(256), 0, stream, mean, init_c_w,
                     init_c_b, c, B_, D_, E_);
  // 6. att1 (plain bf16 MFMA, prefetch + XCD swizzle)
  hipLaunchKernelGGL((mfma_gemm<0, false, true>), dim3(A_ / 128, (B_ * P_) / 128), dim3(256),
                     0, stream, enc, E_, row_map, encattwT, E_, enc_att_b,
                     (const float*)nullptr, att1, A_, B_ * P_, A_, E_, (const int*)nullptr);
  // 7. g_all = emb(tok) @ W_ih[:, :512]^T + b_ih + b_hh   (split bf16 MFMA)
  hipLaunchKernelGGL((mfma_gemm<0, true, false>), dim3((4 * D_) / 128, (T_ * B_) / 128),
                     dim3(256), 0, stream, emb, M_, tok_rows, lstm_w_ih, M_ + E_, lstm_b_ih,
                     lstm_b_hh, g_all, 4 * D_, T_ * B_, 4 * D_, M_, (const int*)nullptr);
  // 8. the whole decode loop: one persistent kernel with slot-based grid barrier
  hipLaunchKernelGGL(loop_kernel, dim3(NBLK_), dim3(256), 0, stream, att1, enc, order,
                     declen, decT, dec_att_b, fbT, f_beta_b, lstm_w_hh, lstm_w_ih,
                     full_att_w, full_att_b, g_all, g_part, gh, h_all, c, xh, gate, att2,
                     alphas_out, bar);
  // 9. batched fc over all (t,b), masked scatter (split bf16 MFMA)
  hipLaunchKernelGGL((mfma_gemm<1, true, false>), dim3((V_ + 127) / 128, (T_ * B_) / 128),
                     dim3(256), 0, stream, h_all + B_ * D_, D_, (const int*)nullptr, fc_w, D_,
                     fc_b, (const float*)nullptr, out, V_, T_ * B_, V_, D_, declen);
}

// Round 7
// 5492.569 us; speedup vs baseline: 1.5669x; 1.5669x over previous
//
#include <hip/hip_runtime.h>
#include <math.h>

#define B_ 128
#define P_ 196
#define E_ 2048
#define D_ 512
#define A_ 512
#define M_ 512
#define V_ 10000
#define L_ 21
#define T_ 20

#define NBLK_ 256
#define SLOTS_WORDS (NBLK_ * 16 + 16)

typedef __attribute__((ext_vector_type(8))) short bf16x8;
typedef __attribute__((ext_vector_type(4))) float f32x4;
typedef unsigned short ushort_t;

// ---------------------------------------------------------------------------
// order kernel: stable argsort by descending caption length (B=128)
// also zeroes the slot-barrier state for the persistent loop kernel
// ---------------------------------------------------------------------------
__global__ void order_kernel(const int* __restrict__ lens, const int* __restrict__ caps,
                             int* __restrict__ order, int* __restrict__ declen,
                             int* __restrict__ row_map, int* __restrict__ tok_rows,
                             unsigned* __restrict__ bar) {
  __shared__ int s_order[B_];
  int tid = threadIdx.x;
  for (int i = tid; i < SLOTS_WORDS; i += 256) bar[i] = 0u;
  if (tid < B_) {
    int li = lens[tid];
    int r = 0;
    for (int j = 0; j < B_; ++j) {
      int lj = lens[j];
      r += (lj > li) || (lj == li && j < tid);
    }
    s_order[r] = tid;
    declen[r] = li - 1;
  }
  __syncthreads();
  if (tid < B_) order[tid] = s_order[tid];
  for (int m = tid; m < B_ * P_; m += blockDim.x) {
    int b = m / P_, p = m - b * P_;
    row_map[m] = s_order[b] * P_ + p;
  }
  for (int i = tid; i < T_ * B_; i += blockDim.x) {
    int t = i >> 7, b = i & 127;
    tok_rows[i] = caps[s_order[b] * L_ + t];
  }
}

// ---------------------------------------------------------------------------
// mean over P of sorted encoder rows
// ---------------------------------------------------------------------------
__global__ void mean_kernel(const float* __restrict__ enc, const int* __restrict__ order,
                            float* __restrict__ mean) {
  int b = blockIdx.y;
  int e = blockIdx.x * blockDim.x + threadIdx.x;
  int ob = order[b];
  const float* base = enc + (long long)ob * P_ * E_ + e;
  float s = 0.f;
  for (int p = 0; p < P_; ++p) s += base[(long long)p * E_];
  mean[b * E_ + e] = s * (1.0f / P_);
}

// ---------------------------------------------------------------------------
// bf16 helpers
// ---------------------------------------------------------------------------
__device__ __forceinline__ unsigned f2bf_u(float f) {
  unsigned u = __float_as_uint(f);
  return (u + 0x7fffu + ((u >> 16) & 1u)) >> 16;
}
__device__ __forceinline__ float bf2f(ushort_t h) {
  return __uint_as_float(((unsigned)h) << 16);
}

// ---------------------------------------------------------------------------
// enc -> bf16 sorted copy: enc_bf[r][e] = bf16(enc[row_map[r]][e]); grid 25088
// ---------------------------------------------------------------------------
__global__ void enc2bf_kernel(const float* __restrict__ enc, const int* __restrict__ row_map,
                              ushort_t* __restrict__ out) {
  int r = blockIdx.x;
  int row = row_map[r];
  const float* src = enc + (long long)row * E_ + threadIdx.x * 8;
  float4 v0 = ((const float4*)src)[0];
  float4 v1 = ((const float4*)src)[1];
  float f[8] = {v0.x, v0.y, v0.z, v0.w, v1.x, v1.y, v1.z, v1.w};
  unsigned h[8];
#pragma unroll
  for (int j = 0; j < 8; ++j) h[j] = f2bf_u(f[j]);
  int4 o;
  o.x = (int)(h[0] | (h[1] << 16));
  o.y = (int)(h[2] | (h[3] << 16));
  o.z = (int)(h[4] | (h[5] << 16));
  o.w = (int)(h[6] | (h[7] << 16));
  *(int4*)(out + (long long)r * E_ + threadIdx.x * 8) = o;
}

// ---------------------------------------------------------------------------
// generic 32x32 fp32 transpose: in [K,N] -> out [N,K];  grid (N/32, K/32)
// ---------------------------------------------------------------------------
__global__ void transpose_kernel(const float* __restrict__ in, float* __restrict__ out,
                                 int K, int N) {
  __shared__ float tt[32][33];
  int bx = blockIdx.x * 32;
  int by = blockIdx.y * 32;
  int lx = threadIdx.x & 31, ly = threadIdx.x >> 5;
#pragma unroll
  for (int i = 0; i < 32; i += 8) tt[ly + i][lx] = in[(long long)(by + ly + i) * N + bx + lx];
  __syncthreads();
#pragma unroll
  for (int i = 0; i < 32; i += 8)
    out[(long long)(bx + ly + i) * K + by + lx] = tt[lx][ly + i];
}

// ---------------------------------------------------------------------------
// fp32 tiled GEMM (h0/c0 init): C = A@B + bias, B row-major [K,N]
// ---------------------------------------------------------------------------
__global__ __launch_bounds__(256) void gemm32_kernel(
    const float* __restrict__ A, const float* __restrict__ Bm,
    const float* __restrict__ bias, float* __restrict__ C, int M, int N, int K) {
  __shared__ float As[16][64];
  __shared__ float Bs[16][64];
  const int tid = threadIdx.x;
  const int bm = blockIdx.y * 64, bn = blockIdx.x * 64;
  const int tm = tid >> 4, tn = tid & 15;
  float acc[4][4];
#pragma unroll
  for (int i = 0; i < 4; ++i)
#pragma unroll
    for (int j = 0; j < 4; ++j) acc[i][j] = 0.f;
  const int lm = tid >> 2;
  const int lk = (tid & 3) * 4;
  for (int k0 = 0; k0 < K; k0 += 16) {
    {
      int m = bm + lm;
      float4 v = make_float4(0.f, 0.f, 0.f, 0.f);
      if (m < M) v = *(const float4*)(A + (long long)m * K + k0 + lk);
      As[lk + 0][lm] = v.x;
      As[lk + 1][lm] = v.y;
      As[lk + 2][lm] = v.z;
      As[lk + 3][lm] = v.w;
    }
    {
      int k = tid >> 4;
      int n4 = (tid & 15) * 4;
      int n = bn + n4;
      float4 v = make_float4(0.f, 0.f, 0.f, 0.f);
      if (n < N) v = *(const float4*)(Bm + (long long)(k0 + k) * N + n);
      Bs[k][n4 + 0] = v.x;
      Bs[k][n4 + 1] = v.y;
      Bs[k][n4 + 2] = v.z;
      Bs[k][n4 + 3] = v.w;
    }
    __syncthreads();
#pragma unroll
    for (int k = 0; k < 16; ++k) {
      float a0 = As[k][tm * 4 + 0], a1 = As[k][tm * 4 + 1];
      float a2 = As[k][tm * 4 + 2], a3 = As[k][tm * 4 + 3];
      float b0 = Bs[k][tn * 4 + 0], b1 = Bs[k][tn * 4 + 1];
      float b2 = Bs[k][tn * 4 + 2], b3 = Bs[k][tn * 4 + 3];
      acc[0][0] += a0 * b0; acc[0][1] += a0 * b1; acc[0][2] += a0 * b2; acc[0][3] += a0 * b3;
      acc[1][0] += a1 * b0; acc[1][1] += a1 * b1; acc[1][2] += a1 * b2; acc[1][3] += a1 * b3;
      acc[2][0] += a2 * b0; acc[2][1] += a2 * b1; acc[2][2] += a2 * b2; acc[2][3] += a2 * b3;
      acc[3][0] += a3 * b0; acc[3][1] += a3 * b1; acc[3][2] += a3 * b2; acc[3][3] += a3 * b3;
    }
    __syncthreads();
  }
#pragma unroll
  for (int i = 0; i < 4; ++i) {
    int m = bm + tm * 4 + i;
    if (m >= M) continue;
#pragma unroll
    for (int j = 0; j < 4; ++j) {
      int n = bn + tn * 4 + j;
      if (n >= N) continue;
      C[(long long)m * N + n] = acc[i][j] + (bias ? bias[n] : 0.f);
    }
  }
}

// stage 16 floats (128-row tiles)
__device__ __forceinline__ void stage16(short* __restrict__ Ph, short* __restrict__ Pl,
                                        int r, int kq, float4 v0, float4 v1, float4 v2,
                                        float4 v3, bool split) {
  float f[16] = {v0.x, v0.y, v0.z, v0.w, v1.x, v1.y, v1.z, v1.w,
                 v2.x, v2.y, v2.z, v2.w, v3.x, v3.y, v3.z, v3.w};
#pragma unroll
  for (int g2 = 0; g2 < 2; ++g2) {
    int gg = (kq >> 3) + g2;
    int slot = gg ^ ((r >> 1) & 3);
    unsigned hb[8];
    float lf[8];
#pragma unroll
    for (int j = 0; j < 8; ++j) {
      float x = f[g2 * 8 + j];
      hb[j] = f2bf_u(x);
      lf[j] = x - __uint_as_float(hb[j] << 16);
    }
    int4 ph;
    ph.x = (int)(hb[0] | (hb[1] << 16));
    ph.y = (int)(hb[2] | (hb[3] << 16));
    ph.z = (int)(hb[4] | (hb[5] << 16));
    ph.w = (int)(hb[6] | (hb[7] << 16));
    *(int4*)&Ph[r * 32 + slot * 8] = ph;
    if (split) {
      unsigned lb[8];
#pragma unroll
      for (int j = 0; j < 8; ++j) lb[j] = f2bf_u(lf[j]);
      int4 pl;
      pl.x = (int)(lb[0] | (lb[1] << 16));
      pl.y = (int)(lb[2] | (lb[3] << 16));
      pl.z = (int)(lb[4] | (lb[5] << 16));
      pl.w = (int)(lb[6] | (lb[7] << 16));
      *(int4*)&Pl[r * 32 + slot * 8] = pl;
    }
  }
}

// stage 8 floats (64-row tiles)
__device__ __forceinline__ void stage8(short* __restrict__ Ph, short* __restrict__ Pl,
                                       int r, int kq8, float4 v0, float4 v1) {
  int slot = kq8 ^ ((r >> 1) & 3);
  float f[8] = {v0.x, v0.y, v0.z, v0.w, v1.x, v1.y, v1.z, v1.w};
  unsigned hb[8];
  float lf[8];
#pragma unroll
  for (int j = 0; j < 8; ++j) {
    hb[j] = f2bf_u(f[j]);
    lf[j] = f[j] - __uint_as_float(hb[j] << 16);
  }
  int4 ph;
  ph.x = (int)(hb[0] | (hb[1] << 16));
  ph.y = (int)(hb[2] | (hb[3] << 16));
  ph.z = (int)(hb[4] | (hb[5] << 16));
  ph.w = (int)(hb[6] | (hb[7] << 16));
  *(int4*)&Ph[r * 32 + slot * 8] = ph;
  unsigned lb[8];
#pragma unroll
  for (int j = 0; j < 8; ++j) lb[j] = f2bf_u(lf[j]);
  int4 pl;
  pl.x = (int)(lb[0] | (lb[1] << 16));
  pl.y = (int)(lb[2] | (lb[3] << 16));
  pl.z = (int)(lb[4] | (lb[5] << 16));
  pl.w = (int)(lb[6] | (lb[7] << 16));
  *(int4*)&Pl[r * 32 + slot * 8] = pl;
}

__device__ __forceinline__ bf16x8 frag_load(const short* __restrict__ P, int row, int g) {
  int slot = g ^ ((row >> 1) & 3);
  return *(const bf16x8*)&P[row * 32 + slot * 8];
}

// ---------------------------------------------------------------------------
// big MFMA GEMM: 128x128 tile, BK=32, register prefetch.
// MODE 0: C[m*ldc+n]     MODE 1: fc masked scatter
// OB: write bf16 (ushort) output instead of fp32
// ---------------------------------------------------------------------------
template <int MODE, bool SPLIT, bool SWZ, bool OB>
__global__ __launch_bounds__(256) void mfma_gemm(
    const float* __restrict__ A, int lda, const int* __restrict__ row_map,
    const float* __restrict__ Bn, int ldb,
    const float* __restrict__ bias, const float* __restrict__ bias2,
    void* __restrict__ Cv, int ldc, int M, int N, int K,
    const int* __restrict__ declen) {
  __shared__ short Ah[128 * 32];
  __shared__ short Bh[128 * 32];
  __shared__ short Al[128 * 32];
  __shared__ short Bl[128 * 32];
  const int tid = threadIdx.x;
  int bxi, byi;
  if (SWZ) {
    int gx = gridDim.x, gy = gridDim.y;
    int id = blockIdx.y * gx + blockIdx.x;
    int super = 8 * gx;
    int body = (gy & ~7) * gx;
    if (id < body) {
      int s = id / super, rem = id % super;
      byi = s * 8 + (rem & 7);
      bxi = rem >> 3;
    } else {
      int rem = id - body;
      byi = (gy & ~7) + rem / gx;
      bxi = rem % gx;
    }
  } else {
    bxi = blockIdx.x;
    byi = blockIdx.y;
  }
  const int bm = byi * 128, bn = bxi * 128;

  f32x4 acc[4][4];
#pragma unroll
  for (int i = 0; i < 4; ++i)
#pragma unroll
    for (int j = 0; j < 4; ++j) acc[i][j] = (f32x4){0.f, 0.f, 0.f, 0.f};

  const int r = tid >> 1;
  const int kq = (tid & 1) * 16;
  const int am = bm + r;
  const long long arow = row_map ? (long long)row_map[am] : (long long)am;
  const float* ap = A + arow * (long long)lda + kq;
  const int gn = bn + r;
  const float* bp = Bn + (long long)gn * ldb + kq;
  const bool bok = gn < N;

  const int lane = tid & 63;
  const int wv = tid >> 6, wr = wv >> 1, wc = wv & 1;
  const int lr = lane & 15, g = lane >> 4;

  float4 z4 = make_float4(0.f, 0.f, 0.f, 0.f);
  float4 a0 = *(const float4*)(ap), a1 = *(const float4*)(ap + 4);
  float4 a2 = *(const float4*)(ap + 8), a3 = *(const float4*)(ap + 12);
  float4 b0 = bok ? *(const float4*)(bp) : z4;
  float4 b1 = bok ? *(const float4*)(bp + 4) : z4;
  float4 b2 = bok ? *(const float4*)(bp + 8) : z4;
  float4 b3 = bok ? *(const float4*)(bp + 12) : z4;

  for (int k0 = 0; k0 < K; k0 += 32) {
    stage16(Ah, Al, r, kq, a0, a1, a2, a3, SPLIT);
    stage16(Bh, Bl, r, kq, b0, b1, b2, b3, SPLIT);
    __syncthreads();
    if (k0 + 32 < K) {
      int kn = k0 + 32;
      a0 = *(const float4*)(ap + kn);
      a1 = *(const float4*)(ap + kn + 4);
      a2 = *(const float4*)(ap + kn + 8);
      a3 = *(const float4*)(ap + kn + 12);
      b0 = bok ? *(const float4*)(bp + kn) : z4;
      b1 = bok ? *(const float4*)(bp + kn + 4) : z4;
      b2 = bok ? *(const float4*)(bp + kn + 8) : z4;
      b3 = bok ? *(const float4*)(bp + kn + 12) : z4;
    }
    bf16x8 ah[4], bh[4];
#pragma unroll
    for (int i = 0; i < 4; ++i) {
      ah[i] = frag_load(Ah, wr * 64 + i * 16 + lr, g);
      bh[i] = frag_load(Bh, wc * 64 + i * 16 + lr, g);
    }
#pragma unroll
    for (int i = 0; i < 4; ++i)
#pragma unroll
      for (int j = 0; j < 4; ++j)
        acc[i][j] = __builtin_amdgcn_mfma_f32_16x16x32_bf16(ah[i], bh[j], acc[i][j], 0, 0, 0);
    if (SPLIT) {
      bf16x8 al2[4], bl2[4];
#pragma unroll
      for (int i = 0; i < 4; ++i) {
        al2[i] = frag_load(Al, wr * 64 + i * 16 + lr, g);
        bl2[i] = frag_load(Bl, wc * 64 + i * 16 + lr, g);
      }
#pragma unroll
      for (int i = 0; i < 4; ++i)
#pragma unroll
        for (int j = 0; j < 4; ++j)
          acc[i][j] = __builtin_amdgcn_mfma_f32_16x16x32_bf16(al2[i], bh[j], acc[i][j], 0, 0, 0);
#pragma unroll
      for (int i = 0; i < 4; ++i)
#pragma unroll
        for (int j = 0; j < 4; ++j)
          acc[i][j] = __builtin_amdgcn_mfma_f32_16x16x32_bf16(ah[i], bl2[j], acc[i][j], 0, 0, 0);
    }
    __syncthreads();
  }

#pragma unroll
  for (int j = 0; j < 4; ++j) {
    int n = bn + wc * 64 + j * 16 + lr;
    float bj = 0.f;
    if (n < N) {
      if (bias) bj += bias[n];
      if (bias2) bj += bias2[n];
    }
#pragma unroll
    for (int i = 0; i < 4; ++i) {
#pragma unroll
      for (int rr = 0; rr < 4; ++rr) {
        int m = bm + wr * 64 + i * 16 + g * 4 + rr;
        float v = acc[i][j][rr] + bj;
        if (MODE == 0) {
          if (OB)
            ((ushort_t*)Cv)[(long long)m * ldc + n] = (ushort_t)f2bf_u(v);
          else
            ((float*)Cv)[(long long)m * ldc + n] = v;
        } else {
          if (n < N) {
            int b = m & 127, t = m >> 7;
            ((float*)Cv)[(long long)b * (T_ * V_) + (long long)t * V_ + n] =
                (t < declen[b]) ? v : 0.f;
          }
        }
      }
    }
  }
}

// ---------------------------------------------------------------------------
// 64x64 split-bf16 MFMA tile (device helper for the persistent loop kernel)
// ---------------------------------------------------------------------------
__device__ __forceinline__ void mfma_tile64(
    const float* __restrict__ ap, const float* __restrict__ bp, int K,
    f32x4 (&acc)[2][2], short* Ah, short* Al, short* Bh, short* Bl,
    int sr, int skq, int wr, int wc, int lr, int g) {
  float4 a0 = *(const float4*)(ap), a1 = *(const float4*)(ap + 4);
  float4 b0 = *(const float4*)(bp), b1 = *(const float4*)(bp + 4);
  for (int k0 = 0; k0 < K; k0 += 32) {
    stage8(Ah, Al, sr, skq, a0, a1);
    stage8(Bh, Bl, sr, skq, b0, b1);
    __syncthreads();
    if (k0 + 32 < K) {
      a0 = *(const float4*)(ap + k0 + 32);
      a1 = *(const float4*)(ap + k0 + 36);
      b0 = *(const float4*)(bp + k0 + 32);
      b1 = *(const float4*)(bp + k0 + 36);
    }
    bf16x8 fah[2], fbh[2], fal[2], fbl[2];
#pragma unroll
    for (int i = 0; i < 2; ++i) {
      fah[i] = frag_load(Ah, wr * 32 + i * 16 + lr, g);
      fal[i] = frag_load(Al, wr * 32 + i * 16 + lr, g);
      fbh[i] = frag_load(Bh, wc * 32 + i * 16 + lr, g);
      fbl[i] = frag_load(Bl, wc * 32 + i * 16 + lr, g);
    }
#pragma unroll
    for (int i = 0; i < 2; ++i)
#pragma unroll
      for (int j = 0; j < 2; ++j) {
        acc[i][j] = __builtin_amdgcn_mfma_f32_16x16x32_bf16(fah[i], fbh[j], acc[i][j], 0, 0, 0);
        acc[i][j] = __builtin_amdgcn_mfma_f32_16x16x32_bf16(fal[i], fbh[j], acc[i][j], 0, 0, 0);
        acc[i][j] = __builtin_amdgcn_mfma_f32_16x16x32_bf16(fah[i], fbl[j], acc[i][j], 0, 0, 0);
      }
    __syncthreads();
  }
}

// ---------------------------------------------------------------------------
// one-hop software grid barrier: every block stores its own padded slot;
// wave 0 of EVERY block polls all 256 slots directly (no master round-trip).
// monotonic targets; state zeroed each call by order_kernel
// ---------------------------------------------------------------------------
__device__ __forceinline__ void gsync(unsigned* __restrict__ slots, unsigned target) {
  __syncthreads();
  if (threadIdx.x == 0) {
    __threadfence();
    __hip_atomic_store(&slots[blockIdx.x * 16], target, __ATOMIC_RELEASE,
                       __HIP_MEMORY_SCOPE_AGENT);
  }
  if (threadIdx.x < 64) {
#pragma unroll
    for (int k = 0; k < 4; ++k) {
      unsigned idx = ((unsigned)threadIdx.x * 4 + k) * 16;
      while (__hip_atomic_load(&slots[idx], __ATOMIC_ACQUIRE, __HIP_MEMORY_SCOPE_AGENT) <
             target) {
        __builtin_amdgcn_s_sleep(2);
      }
    }
    __threadfence();
  }
  __syncthreads();
}

// ---------------------------------------------------------------------------
// persistent kernel: the whole 20-step decoder loop, 256 blocks x 256 threads
// ENCBF: att1/enc read as bf16 (L3-resident working set)
// ---------------------------------------------------------------------------
template <bool ENCBF>
__global__ __launch_bounds__(256, 1) void loop_kernel(
    const float* __restrict__ att1f, const ushort_t* __restrict__ att1b,
    const float* __restrict__ encf, const ushort_t* __restrict__ encb,
    const int* __restrict__ order, const int* __restrict__ declen,
    const float* __restrict__ decT, const float* __restrict__ decb,
    const float* __restrict__ fbT, const float* __restrict__ fbb,
    const float* __restrict__ whh, const float* __restrict__ wih,
    const float* __restrict__ faw, const float* __restrict__ fab,
    const float* __restrict__ g_all, float* __restrict__ g_part,
    float* __restrict__ gh, float* __restrict__ h_all, float* __restrict__ c,
    float* __restrict__ xh, float* __restrict__ gate, float* __restrict__ att2,
    float* __restrict__ alphas_out, unsigned* __restrict__ bar) {
  __shared__ short Ah[64 * 32];
  __shared__ short Bh[64 * 32];
  __shared__ short Al[64 * 32];
  __shared__ short Bl[64 * 32];
  __shared__ float att2_s[512];
  __shared__ float w_s[512];
  __shared__ float e_s[P_];
  __shared__ float red[8];

  unsigned* slots = bar;
  unsigned tgt = 0;

  const int bid = blockIdx.x, tid = threadIdx.x;
  const int lane = tid & 63, wv = tid >> 6, wr = wv >> 1, wc = wv & 1;
  const int lr = lane & 15, g = lane >> 4;
  const int sr = tid >> 2, skq = tid & 3;

  const float fb0 = fab[0];
  // bf16 path: per-lane 8-col register slice of full_att_w (constant over t)
  float wr8[8];
  if (ENCBF) {
    const float4* wp = (const float4*)(faw + lane * 8);
#pragma unroll
    for (int q = 0; q < 2; ++q) {
      float4 v = wp[q];
      wr8[q * 4 + 0] = v.x;
      wr8[q * 4 + 1] = v.y;
      wr8[q * 4 + 2] = v.z;
      wr8[q * 4 + 3] = v.w;
    }
  }

  for (int t = 0; t < T_; ++t) {
    const float* h_cur = h_all + t * (B_ * D_);
    // ---------------- phase A ----------------
    if (bid < 144) {
      int nt = bid % 72, mt = bid / 72;
      int bn = nt * 64;
      const float* Bb;
      if (bn < 512) Bb = decT + bn * 512;
      else if (bn < 2560) Bb = fbT + (bn - 512) * 512;
      else Bb = whh + (bn - 2560) * 512;
      f32x4 acc[2][2];
#pragma unroll
      for (int i = 0; i < 2; ++i)
#pragma unroll
        for (int j = 0; j < 2; ++j) acc[i][j] = (f32x4){0.f, 0.f, 0.f, 0.f};
      mfma_tile64(h_cur + (mt * 64 + sr) * 512 + skq * 8, Bb + sr * 512 + skq * 8, 512,
                  acc, Ah, Al, Bh, Bl, sr, skq, wr, wc, lr, g);
#pragma unroll
      for (int j = 0; j < 2; ++j) {
        int n = bn + wc * 32 + j * 16 + lr;
#pragma unroll
        for (int i = 0; i < 2; ++i) {
#pragma unroll
          for (int rr = 0; rr < 4; ++rr) {
            int m = mt * 64 + wr * 32 + i * 16 + g * 4 + rr;
            float v = acc[i][j][rr];
            if (bn < 512) {
              att2[m * 512 + n] = v + decb[n];
            } else if (bn < 2560) {
              int nc = n - 512;
              gate[m * 2048 + nc] = 1.f / (1.f + __expf(-(v + fbb[nc])));
            } else {
              gh[m * 2048 + (n - 2560)] = v;
            }
          }
        }
      }
    }
    gsync(slots, ++tgt);
    // ---------------- phase B ----------------
    {
      const int b = bid & 127, half = bid >> 7;
      if (ENCBF) {
        // e-comp: lane owns cols [lane*8, lane*8+8); att2 preloaded to regs
        float a2r[8];
        const float4* a2p = (const float4*)(att2 + b * 512 + lane * 8);
#pragma unroll
        for (int q = 0; q < 2; ++q) {
          float4 v = a2p[q];
          a2r[q * 4 + 0] = v.x;
          a2r[q * 4 + 1] = v.y;
          a2r[q * 4 + 2] = v.z;
          a2r[q * 4 + 3] = v.w;
        }
        for (int p = wv; p < P_; p += 4) {
          const ushort_t* row = att1b + ((long long)(b * P_ + p)) * 512 + lane * 8;
          bf16x8 hv = *(const bf16x8*)row;
          float s = 0.f;
#pragma unroll
          for (int j = 0; j < 8; ++j) {
            float x = bf2f((ushort_t)hv[j]) + a2r[j];
            s += (x > 0.f ? x : 0.f) * wr8[j];
          }
          for (int off = 32; off; off >>= 1) s += __shfl_down(s, off);
          if (lane == 0) e_s[p] = s + fb0;
        }
      } else {
        for (int i = tid; i < 512; i += 256) {
          att2_s[i] = att2[b * 512 + i];
          w_s[i] = faw[i];
        }
        __syncthreads();
        for (int p = wv; p < P_; p += 4) {
          const float* row = att1f + ((long long)b * P_ + p) * 512;
          float s = 0.f;
#pragma unroll
          for (int i2 = 0; i2 < 8; ++i2) {
            int ix = lane + i2 * 64;
            float v = row[ix] + att2_s[ix];
            s += (v > 0.f ? v : 0.f) * w_s[ix];
          }
          for (int off = 32; off; off >>= 1) s += __shfl_down(s, off);
          if (lane == 0) e_s[p] = s + fb0;
        }
      }
      __syncthreads();
      float mx = -1e30f;
      for (int p = tid; p < P_; p += 256) mx = fmaxf(mx, e_s[p]);
      for (int off = 32; off; off >>= 1) mx = fmaxf(mx, __shfl_down(mx, off));
      if (lane == 0) red[wv] = mx;
      __syncthreads();
      mx = fmaxf(fmaxf(red[0], red[1]), fmaxf(red[2], red[3]));
      float ssum = 0.f;
      for (int p = tid; p < P_; p += 256) {
        float ev = __expf(e_s[p] - mx);
        e_s[p] = ev;
        ssum += ev;
      }
      for (int off = 32; off; off >>= 1) ssum += __shfl_down(ssum, off);
      if (lane == 0) red[4 + wv] = ssum;
      __syncthreads();
      float inv = 1.f / (red[4] + red[5] + red[6] + red[7]);
      const bool active = (t < declen[b]);
      for (int p = tid; p < P_; p += 256) {
        float al = e_s[p] * inv;
        e_s[p] = al;
        if (half == 0)
          alphas_out[(long long)b * (T_ * P_) + t * P_ + p] = active ? al : 0.f;
      }
      __syncthreads();
      if (ENCBF) {
        const ushort_t* eb = encb + (long long)b * (P_ * E_);
        int col = half * 1024 + tid * 4;
        float s0 = 0.f, s1 = 0.f, s2 = 0.f, s3 = 0.f;
#pragma unroll 8
        for (int p = 0; p < P_; ++p) {
          short4 hv = *(const short4*)(eb + (long long)p * E_ + col);
          float a = e_s[p];
          s0 += a * bf2f((ushort_t)hv.x);
          s1 += a * bf2f((ushort_t)hv.y);
          s2 += a * bf2f((ushort_t)hv.z);
          s3 += a * bf2f((ushort_t)hv.w);
        }
        float4 gv = *(const float4*)(gate + b * 2048 + col);
        float4 o;
        o.x = gv.x * s0;
        o.y = gv.y * s1;
        o.z = gv.z * s2;
        o.w = gv.w * s3;
        *(float4*)(xh + b * 2048 + col) = o;
      } else {
        const int ob = order[b];
        const float* eb = encf + (long long)ob * (P_ * E_);
        for (int e0 = half * 1024 + tid; e0 < half * 1024 + 1024; e0 += 256) {
          float s2 = 0.f;
#pragma unroll 4
          for (int p = 0; p < P_; ++p) s2 += e_s[p] * eb[p * 2048 + e0];
          xh[b * 2048 + e0] = gate[b * 2048 + e0] * s2;
        }
      }
    }
    gsync(slots, ++tgt);
    // ---------------- phase C ----------------
    {
      int kc = bid >> 6, rem = bid & 63, mt = rem >> 5, nt = rem & 31;
      int bn = nt * 64;
      f32x4 acc[2][2];
#pragma unroll
      for (int i = 0; i < 2; ++i)
#pragma unroll
        for (int j = 0; j < 2; ++j) acc[i][j] = (f32x4){0.f, 0.f, 0.f, 0.f};
      mfma_tile64(xh + (mt * 64 + sr) * 2048 + kc * 512 + skq * 8,
                  wih + (long long)(bn + sr) * 2560 + 512 + kc * 512 + skq * 8, 512,
                  acc, Ah, Al, Bh, Bl, sr, skq, wr, wc, lr, g);
      float* gp = g_part + kc * (128 * 2048);
#pragma unroll
      for (int j = 0; j < 2; ++j) {
        int n = bn + wc * 32 + j * 16 + lr;
#pragma unroll
        for (int i = 0; i < 2; ++i) {
#pragma unroll
          for (int rr = 0; rr < 4; ++rr) {
            int m = mt * 64 + wr * 32 + i * 16 + g * 4 + rr;
            gp[m * 2048 + n] = acc[i][j][rr];
          }
        }
      }
    }
    gsync(slots, ++tgt);
    // ---------------- phase D ----------------
    {
      int idx = bid * 256 + tid;
      int b = idx >> 9, d = idx & 511;
      int base = b * 2048 + d;
      const float* ge = g_all + (long long)t * (128 * 2048);
      float gi = ge[base] + gh[base];
      float gf2 = ge[base + 512] + gh[base + 512];
      float gg2 = ge[base + 1024] + gh[base + 1024];
      float go = ge[base + 1536] + gh[base + 1536];
#pragma unroll
      for (int kc = 0; kc < 4; ++kc) {
        const float* gp = g_part + kc * (128 * 2048) + base;
        gi += gp[0];
        gf2 += gp[512];
        gg2 += gp[1024];
        go += gp[1536];
      }
      float si = 1.f / (1.f + __expf(-gi));
      float sf = 1.f / (1.f + __expf(-gf2));
      float so = 1.f / (1.f + __expf(-go));
      float cn = sf * c[idx] + si * tanhf(gg2);
      float hn = so * tanhf(cn);
      c[idx] = cn;
      h_all[(t + 1) * (B_ * D_) + idx] = hn;
    }
    gsync(slots, ++tgt);
  }
}

// ---------------------------------------------------------------------------
// launch
// ---------------------------------------------------------------------------
extern "C" void kernel_launch(void* const* d_in, const int* in_sizes, int n_in,
                              void* d_out, int out_size, void* d_ws, size_t ws_size,
                              hipStream_t stream) {
  const float* enc       = (const float*)d_in[0];
  const int*   caps      = (const int*)d_in[1];
  const int*   lens      = (const int*)d_in[2];
  const float* emb       = (const float*)d_in[3];
  const float* enc_att_w = (const float*)d_in[4];
  const float* enc_att_b = (const float*)d_in[5];
  const float* dec_att_w = (const float*)d_in[6];
  const float* dec_att_b = (const float*)d_in[7];
  const float* full_att_w = (const float*)d_in[8];
  const float* full_att_b = (const float*)d_in[9];
  const float* init_h_w  = (const float*)d_in[10];
  const float* init_h_b  = (const float*)d_in[11];
  const float* init_c_w  = (const float*)d_in[12];
  const float* init_c_b  = (const float*)d_in[13];
  const float* f_beta_w  = (const float*)d_in[14];
  const float* f_beta_b  = (const float*)d_in[15];
  const float* lstm_w_ih = (const float*)d_in[16];
  const float* lstm_b_ih = (const float*)d_in[17];
  const float* lstm_w_hh = (const float*)d_in[18];
  const float* lstm_b_hh = (const float*)d_in[19];
  const float* fc_w      = (const float*)d_in[20];
  const float* fc_b      = (const float*)d_in[21];

  float* out = (float*)d_out;
  float* alphas_out = out + (long long)B_ * T_ * V_;

  // scratch in the (dead until final fc) preds region of d_out
  float* g_all    = out;                                 // 5.24M floats
  float* g_part   = out + 6 * 1024 * 1024;               // 1.05M
  float* encattwT = out + 8 * 1024 * 1024;               // [512][2048]
  float* decT     = out + 9 * 1024 * 1024 + 512 * 1024;  // [512][512]
  float* fbT      = decT + 512 * 512;                    // [2048][512]
  float* gh       = out + 12 * 1024 * 1024;              // [128][2048]

  // workspace layout (cursor-based; bf path needs ~138 MB, fallback ~64 MB)
  size_t cur = 0;
  char* wsb = (char*)d_ws;
  auto alloc = [&](size_t bytes) {
    size_t off = cur;
    cur = (cur + bytes + 255) & ~(size_t)255;
    return (void*)(wsb + off);
  };
  const size_t ATT1B_BYTES = (size_t)B_ * P_ * A_ * 2;        // 25.7 MB
  const size_t ENCB_BYTES  = (size_t)B_ * P_ * E_ * 2;        // 102.8 MB
  const size_t ATT1F_BYTES = (size_t)B_ * P_ * A_ * 4;        // 51.4 MB
  const size_t REST_BYTES  = (size_t)(B_ * E_ + (T_ + 1) * B_ * D_ + B_ * D_ + B_ * A_ +
                                      B_ * E_ + B_ * E_) * 4 +
                             (2 * B_ + B_ * P_ + T_ * B_ + SLOTS_WORDS + 64) * 4 + 4096;
  const bool bfpath = ws_size >= ATT1B_BYTES + ENCB_BYTES + REST_BYTES + (1u << 20);

  ushort_t* att1b = nullptr;
  ushort_t* encbf = nullptr;
  float* att1f = nullptr;
  if (bfpath) {
    att1b = (ushort_t*)alloc(ATT1B_BYTES);
    encbf = (ushort_t*)alloc(ENCB_BYTES);
  } else {
    att1f = (float*)alloc(ATT1F_BYTES);
  }
  float* mean  = (float*)alloc((size_t)B_ * E_ * 4);
  float* h_all = (float*)alloc((size_t)(T_ + 1) * B_ * D_ * 4);
  float* c     = (float*)alloc((size_t)B_ * D_ * 4);
  float* att2  = (float*)alloc((size_t)B_ * A_ * 4);
  float* gate  = (float*)alloc((size_t)B_ * E_ * 4);
  float* xh    = (float*)alloc((size_t)B_ * E_ * 4);
  int* order   = (int*)alloc(B_ * 4);
  int* declen  = (int*)alloc(B_ * 4);
  int* row_map = (int*)alloc((size_t)B_ * P_ * 4);
  int* tok_rows = (int*)alloc((size_t)T_ * B_ * 4);
  unsigned* bar = (unsigned*)alloc(SLOTS_WORDS * 4);

  // 1. sort + index maps + barrier reset
  hipLaunchKernelGGL(order_kernel, dim3(1), dim3(256), 0, stream, lens, caps, order, declen,
                     row_map, tok_rows, bar);
  // 2. weight transposes ([K,N] -> [N,K])
  hipLaunchKernelGGL(transpose_kernel, dim3(16, 64), dim3(256), 0, stream, enc_att_w,
                     encattwT, E_, A_);
  hipLaunchKernelGGL(transpose_kernel, dim3(16, 16), dim3(256), 0, stream, dec_att_w, decT,
                     D_, A_);
  hipLaunchKernelGGL(transpose_kernel, dim3(64, 16), dim3(256), 0, stream, f_beta_w, fbT,
                     D_, E_);
  // 3. mean
  hipLaunchKernelGGL(mean_kernel, dim3(E_ / 256, B_), dim3(256), 0, stream, enc, order, mean);
  // 4/5. h0, c0 (fp32)
  hipLaunchKernelGGL(gemm32_kernel, dim3(D_ / 64, 2), dim3(256), 0, stream, mean, init_h_w,
                     init_h_b, h_all, B_, D_, E_);
  hipLaunchKernelGGL(gemm32_kernel, dim3(D_ / 64, 2), dim3(256), 0, stream, mean, init_c_w,
                     init_c_b, c, B_, D_, E_);
  // 6. att1 (plain bf16 MFMA; bf path emits bf16 output)
  if (bfpath) {
    hipLaunchKernelGGL((mfma_gemm<0, false, true, true>), dim3(A_ / 128, (B_ * P_) / 128),
                       dim3(256), 0, stream, enc, E_, row_map, encattwT, E_, enc_att_b,
                       (const float*)nullptr, (void*)att1b, A_, B_ * P_, A_, E_,
                       (const int*)nullptr);
    // 6b. enc -> bf16 sorted copy
    hipLaunchKernelGGL(enc2bf_kernel, dim3(B_ * P_), dim3(256), 0, stream, enc, row_map,
                       encbf);
  } else {
    hipLaunchKernelGGL((mfma_gemm<0, false, true, false>), dim3(A_ / 128, (B_ * P_) / 128),
                       dim3(256), 0, stream, enc, E_, row_map, encattwT, E_, enc_att_b,
                       (const float*)nullptr, (void*)att1f, A_, B_ * P_, A_, E_,
                       (const int*)nullptr);
  }
  // 7. g_all = emb(tok) @ W_ih[:, :512]^T + b_ih + b_hh   (split bf16 MFMA)
  hipLaunchKernelGGL((mfma_gemm<0, true, false, false>), dim3((4 * D_) / 128, (T_ * B_) / 128),
                     dim3(256), 0, stream, emb, M_, tok_rows, lstm_w_ih, M_ + E_, lstm_b_ih,
                     lstm_b_hh, (void*)g_all, 4 * D_, T_ * B_, 4 * D_, M_,
                     (const int*)nullptr);
  // 8. the decode loop: one persistent kernel with one-hop slot barrier
  if (bfpath) {
    hipLaunchKernelGGL((loop_kernel<true>), dim3(NBLK_), dim3(256), 0, stream,
                       (const float*)nullptr, att1b, (const float*)nullptr, encbf, order,
                       declen, decT, dec_att_b, fbT, f_beta_b, lstm_w_hh, lstm_w_ih,
                       full_att_w, full_att_b, g_all, g_part, gh, h_all, c, xh, gate, att2,
                       alphas_out, bar);
  } else {
    hipLaunchKernelGGL((loop_kernel<false>), dim3(NBLK_), dim3(256), 0, stream, att1f,
                       (const ushort_t*)nullptr, enc, (const ushort_t*)nullptr, order,
                       declen, decT, dec_att_b, fbT, f_beta_b, lstm_w_hh, lstm_w_ih,
                       full_att_w, full_att_b, g_all, g_part, gh, h_all, c, xh, gate, att2,
                       alphas_out, bar);
  }
  // 9. batched fc over all (t,b), masked scatter (split bf16 MFMA)
  hipLaunchKernelGGL((mfma_gemm<1, true, false, false>), dim3((V_ + 127) / 128,
                     (T_ * B_) / 128), dim3(256), 0, stream, h_all + B_ * D_, D_,
                     (const int*)nullptr, fc_w, D_, fc_b, (const float*)nullptr, (void*)out,
                     V_, T_ * B_, V_, D_, declen);
}

// Round 8
// 5078.237 us; speedup vs baseline: 1.6948x; 1.0816x over previous
//
#include <hip/hip_runtime.h>
#include <math.h>

#define B_ 128
#define P_ 196
#define E_ 2048
#define D_ 512
#define A_ 512
#define M_ 512
#define V_ 10000
#define L_ 21
#define T_ 20

#define NBLK_ 256
#define SLOTS_WORDS (NBLK_ * 16 + 16)

typedef __attribute__((ext_vector_type(8))) short bf16x8;
typedef __attribute__((ext_vector_type(4))) float f32x4;
typedef unsigned short ushort_t;

// ---------------------------------------------------------------------------
// order kernel: stable argsort by descending caption length (B=128)
// also zeroes the slot-barrier state for the persistent loop kernel
// ---------------------------------------------------------------------------
__global__ void order_kernel(const int* __restrict__ lens, const int* __restrict__ caps,
                             int* __restrict__ order, int* __restrict__ declen,
                             int* __restrict__ row_map, int* __restrict__ tok_rows,
                             unsigned* __restrict__ bar) {
  __shared__ int s_order[B_];
  int tid = threadIdx.x;
  for (int i = tid; i < SLOTS_WORDS; i += 256) bar[i] = 0u;
  if (tid < B_) {
    int li = lens[tid];
    int r = 0;
    for (int j = 0; j < B_; ++j) {
      int lj = lens[j];
      r += (lj > li) || (lj == li && j < tid);
    }
    s_order[r] = tid;
    declen[r] = li - 1;
  }
  __syncthreads();
  if (tid < B_) order[tid] = s_order[tid];
  for (int m = tid; m < B_ * P_; m += blockDim.x) {
    int b = m / P_, p = m - b * P_;
    row_map[m] = s_order[b] * P_ + p;
  }
  for (int i = tid; i < T_ * B_; i += blockDim.x) {
    int t = i >> 7, b = i & 127;
    tok_rows[i] = caps[s_order[b] * L_ + t];
  }
}

// ---------------------------------------------------------------------------
// mean over P of sorted encoder rows
// ---------------------------------------------------------------------------
__global__ void mean_kernel(const float* __restrict__ enc, const int* __restrict__ order,
                            float* __restrict__ mean) {
  int b = blockIdx.y;
  int e = blockIdx.x * blockDim.x + threadIdx.x;
  int ob = order[b];
  const float* base = enc + (long long)ob * P_ * E_ + e;
  float s = 0.f;
  for (int p = 0; p < P_; ++p) s += base[(long long)p * E_];
  mean[b * E_ + e] = s * (1.0f / P_);
}

// ---------------------------------------------------------------------------
// bf16 helpers
// ---------------------------------------------------------------------------
__device__ __forceinline__ unsigned f2bf_u(float f) {
  unsigned u = __float_as_uint(f);
  return (u + 0x7fffu + ((u >> 16) & 1u)) >> 16;
}
__device__ __forceinline__ float bf2f(ushort_t h) {
  return __uint_as_float(((unsigned)h) << 16);
}

// ---------------------------------------------------------------------------
// enc -> bf16 sorted copy: enc_bf[r][e] = bf16(enc[row_map[r]][e]); grid 25088
// ---------------------------------------------------------------------------
__global__ void enc2bf_kernel(const float* __restrict__ enc, const int* __restrict__ row_map,
                              ushort_t* __restrict__ out) {
  int r = blockIdx.x;
  int row = row_map[r];
  const float* src = enc + (long long)row * E_ + threadIdx.x * 8;
  float4 v0 = ((const float4*)src)[0];
  float4 v1 = ((const float4*)src)[1];
  float f[8] = {v0.x, v0.y, v0.z, v0.w, v1.x, v1.y, v1.z, v1.w};
  unsigned h[8];
#pragma unroll
  for (int j = 0; j < 8; ++j) h[j] = f2bf_u(f[j]);
  int4 o;
  o.x = (int)(h[0] | (h[1] << 16));
  o.y = (int)(h[2] | (h[3] << 16));
  o.z = (int)(h[4] | (h[5] << 16));
  o.w = (int)(h[6] | (h[7] << 16));
  *(int4*)(out + (long long)r * E_ + threadIdx.x * 8) = o;
}

// ---------------------------------------------------------------------------
// generic 32x32 fp32 transpose: in [K,N] -> out [N,K];  grid (N/32, K/32)
// ---------------------------------------------------------------------------
__global__ void transpose_kernel(const float* __restrict__ in, float* __restrict__ out,
                                 int K, int N) {
  __shared__ float tt[32][33];
  int bx = blockIdx.x * 32;
  int by = blockIdx.y * 32;
  int lx = threadIdx.x & 31, ly = threadIdx.x >> 5;
#pragma unroll
  for (int i = 0; i < 32; i += 8) tt[ly + i][lx] = in[(long long)(by + ly + i) * N + bx + lx];
  __syncthreads();
#pragma unroll
  for (int i = 0; i < 32; i += 8)
    out[(long long)(bx + ly + i) * K + by + lx] = tt[lx][ly + i];
}

// ---------------------------------------------------------------------------
// fp32 tiled GEMM (h0/c0 init): C = A@B + bias, B row-major [K,N]
// ---------------------------------------------------------------------------
__global__ __launch_bounds__(256) void gemm32_kernel(
    const float* __restrict__ A, const float* __restrict__ Bm,
    const float* __restrict__ bias, float* __restrict__ C, int M, int N, int K) {
  __shared__ float As[16][64];
  __shared__ float Bs[16][64];
  const int tid = threadIdx.x;
  const int bm = blockIdx.y * 64, bn = blockIdx.x * 64;
  const int tm = tid >> 4, tn = tid & 15;
  float acc[4][4];
#pragma unroll
  for (int i = 0; i < 4; ++i)
#pragma unroll
    for (int j = 0; j < 4; ++j) acc[i][j] = 0.f;
  const int lm = tid >> 2;
  const int lk = (tid & 3) * 4;
  for (int k0 = 0; k0 < K; k0 += 16) {
    {
      int m = bm + lm;
      float4 v = make_float4(0.f, 0.f, 0.f, 0.f);
      if (m < M) v = *(const float4*)(A + (long long)m * K + k0 + lk);
      As[lk + 0][lm] = v.x;
      As[lk + 1][lm] = v.y;
      As[lk + 2][lm] = v.z;
      As[lk + 3][lm] = v.w;
    }
    {
      int k = tid >> 4;
      int n4 = (tid & 15) * 4;
      int n = bn + n4;
      float4 v = make_float4(0.f, 0.f, 0.f, 0.f);
      if (n < N) v = *(const float4*)(Bm + (long long)(k0 + k) * N + n);
      Bs[k][n4 + 0] = v.x;
      Bs[k][n4 + 1] = v.y;
      Bs[k][n4 + 2] = v.z;
      Bs[k][n4 + 3] = v.w;
    }
    __syncthreads();
#pragma unroll
    for (int k = 0; k < 16; ++k) {
      float a0 = As[k][tm * 4 + 0], a1 = As[k][tm * 4 + 1];
      float a2 = As[k][tm * 4 + 2], a3 = As[k][tm * 4 + 3];
      float b0 = Bs[k][tn * 4 + 0], b1 = Bs[k][tn * 4 + 1];
      float b2 = Bs[k][tn * 4 + 2], b3 = Bs[k][tn * 4 + 3];
      acc[0][0] += a0 * b0; acc[0][1] += a0 * b1; acc[0][2] += a0 * b2; acc[0][3] += a0 * b3;
      acc[1][0] += a1 * b0; acc[1][1] += a1 * b1; acc[1][2] += a1 * b2; acc[1][3] += a1 * b3;
      acc[2][0] += a2 * b0; acc[2][1] += a2 * b1; acc[2][2] += a2 * b2; acc[2][3] += a2 * b3;
      acc[3][0] += a3 * b0; acc[3][1] += a3 * b1; acc[3][2] += a3 * b2; acc[3][3] += a3 * b3;
    }
    __syncthreads();
  }
#pragma unroll
  for (int i = 0; i < 4; ++i) {
    int m = bm + tm * 4 + i;
    if (m >= M) continue;
#pragma unroll
    for (int j = 0; j < 4; ++j) {
      int n = bn + tn * 4 + j;
      if (n >= N) continue;
      C[(long long)m * N + n] = acc[i][j] + (bias ? bias[n] : 0.f);
    }
  }
}

// stage 16 floats (128-row tiles)
__device__ __forceinline__ void stage16(short* __restrict__ Ph, short* __restrict__ Pl,
                                        int r, int kq, float4 v0, float4 v1, float4 v2,
                                        float4 v3, bool split) {
  float f[16] = {v0.x, v0.y, v0.z, v0.w, v1.x, v1.y, v1.z, v1.w,
                 v2.x, v2.y, v2.z, v2.w, v3.x, v3.y, v3.z, v3.w};
#pragma unroll
  for (int g2 = 0; g2 < 2; ++g2) {
    int gg = (kq >> 3) + g2;
    int slot = gg ^ ((r >> 1) & 3);
    unsigned hb[8];
    float lf[8];
#pragma unroll
    for (int j = 0; j < 8; ++j) {
      float x = f[g2 * 8 + j];
      hb[j] = f2bf_u(x);
      lf[j] = x - __uint_as_float(hb[j] << 16);
    }
    int4 ph;
    ph.x = (int)(hb[0] | (hb[1] << 16));
    ph.y = (int)(hb[2] | (hb[3] << 16));
    ph.z = (int)(hb[4] | (hb[5] << 16));
    ph.w = (int)(hb[6] | (hb[7] << 16));
    *(int4*)&Ph[r * 32 + slot * 8] = ph;
    if (split) {
      unsigned lb[8];
#pragma unroll
      for (int j = 0; j < 8; ++j) lb[j] = f2bf_u(lf[j]);
      int4 pl;
      pl.x = (int)(lb[0] | (lb[1] << 16));
      pl.y = (int)(lb[2] | (lb[3] << 16));
      pl.z = (int)(lb[4] | (lb[5] << 16));
      pl.w = (int)(lb[6] | (lb[7] << 16));
      *(int4*)&Pl[r * 32 + slot * 8] = pl;
    }
  }
}

// stage 8 floats (64-row tiles)
__device__ __forceinline__ void stage8(short* __restrict__ Ph, short* __restrict__ Pl,
                                       int r, int kq8, float4 v0, float4 v1) {
  int slot = kq8 ^ ((r >> 1) & 3);
  float f[8] = {v0.x, v0.y, v0.z, v0.w, v1.x, v1.y, v1.z, v1.w};
  unsigned hb[8];
  float lf[8];
#pragma unroll
  for (int j = 0; j < 8; ++j) {
    hb[j] = f2bf_u(f[j]);
    lf[j] = f[j] - __uint_as_float(hb[j] << 16);
  }
  int4 ph;
  ph.x = (int)(hb[0] | (hb[1] << 16));
  ph.y = (int)(hb[2] | (hb[3] << 16));
  ph.z = (int)(hb[4] | (hb[5] << 16));
  ph.w = (int)(hb[6] | (hb[7] << 16));
  *(int4*)&Ph[r * 32 + slot * 8] = ph;
  unsigned lb[8];
#pragma unroll
  for (int j = 0; j < 8; ++j) lb[j] = f2bf_u(lf[j]);
  int4 pl;
  pl.x = (int)(lb[0] | (lb[1] << 16));
  pl.y = (int)(lb[2] | (lb[3] << 16));
  pl.z = (int)(lb[4] | (lb[5] << 16));
  pl.w = (int)(lb[6] | (lb[7] << 16));
  *(int4*)&Pl[r * 32 + slot * 8] = pl;
}

__device__ __forceinline__ bf16x8 frag_load(const short* __restrict__ P, int row, int g) {
  int slot = g ^ ((row >> 1) & 3);
  return *(const bf16x8*)&P[row * 32 + slot * 8];
}

// ---------------------------------------------------------------------------
// big MFMA GEMM: 128x128 tile, BK=32, register prefetch.
// MODE 0: C[m*ldc+n]     MODE 1: fc masked scatter
// OB: write bf16 (ushort) output instead of fp32
// ---------------------------------------------------------------------------
template <int MODE, bool SPLIT, bool SWZ, bool OB>
__global__ __launch_bounds__(256) void mfma_gemm(
    const float* __restrict__ A, int lda, const int* __restrict__ row_map,
    const float* __restrict__ Bn, int ldb,
    const float* __restrict__ bias, const float* __restrict__ bias2,
    void* __restrict__ Cv, int ldc, int M, int N, int K,
    const int* __restrict__ declen) {
  __shared__ short Ah[128 * 32];
  __shared__ short Bh[128 * 32];
  __shared__ short Al[128 * 32];
  __shared__ short Bl[128 * 32];
  const int tid = threadIdx.x;
  int bxi, byi;
  if (SWZ) {
    int gx = gridDim.x, gy = gridDim.y;
    int id = blockIdx.y * gx + blockIdx.x;
    int super = 8 * gx;
    int body = (gy & ~7) * gx;
    if (id < body) {
      int s = id / super, rem = id % super;
      byi = s * 8 + (rem & 7);
      bxi = rem >> 3;
    } else {
      int rem = id - body;
      byi = (gy & ~7) + rem / gx;
      bxi = rem % gx;
    }
  } else {
    bxi = blockIdx.x;
    byi = blockIdx.y;
  }
  const int bm = byi * 128, bn = bxi * 128;

  f32x4 acc[4][4];
#pragma unroll
  for (int i = 0; i < 4; ++i)
#pragma unroll
    for (int j = 0; j < 4; ++j) acc[i][j] = (f32x4){0.f, 0.f, 0.f, 0.f};

  const int r = tid >> 1;
  const int kq = (tid & 1) * 16;
  const int am = bm + r;
  const long long arow = row_map ? (long long)row_map[am] : (long long)am;
  const float* ap = A + arow * (long long)lda + kq;
  const int gn = bn + r;
  const float* bp = Bn + (long long)gn * ldb + kq;
  const bool bok = gn < N;

  const int lane = tid & 63;
  const int wv = tid >> 6, wr = wv >> 1, wc = wv & 1;
  const int lr = lane & 15, g = lane >> 4;

  float4 z4 = make_float4(0.f, 0.f, 0.f, 0.f);
  float4 a0 = *(const float4*)(ap), a1 = *(const float4*)(ap + 4);
  float4 a2 = *(const float4*)(ap + 8), a3 = *(const float4*)(ap + 12);
  float4 b0 = bok ? *(const float4*)(bp) : z4;
  float4 b1 = bok ? *(const float4*)(bp + 4) : z4;
  float4 b2 = bok ? *(const float4*)(bp + 8) : z4;
  float4 b3 = bok ? *(const float4*)(bp + 12) : z4;

  for (int k0 = 0; k0 < K; k0 += 32) {
    stage16(Ah, Al, r, kq, a0, a1, a2, a3, SPLIT);
    stage16(Bh, Bl, r, kq, b0, b1, b2, b3, SPLIT);
    __syncthreads();
    if (k0 + 32 < K) {
      int kn = k0 + 32;
      a0 = *(const float4*)(ap + kn);
      a1 = *(const float4*)(ap + kn + 4);
      a2 = *(const float4*)(ap + kn + 8);
      a3 = *(const float4*)(ap + kn + 12);
      b0 = bok ? *(const float4*)(bp + kn) : z4;
      b1 = bok ? *(const float4*)(bp + kn + 4) : z4;
      b2 = bok ? *(const float4*)(bp + kn + 8) : z4;
      b3 = bok ? *(const float4*)(bp + kn + 12) : z4;
    }
    bf16x8 ah[4], bh[4];
#pragma unroll
    for (int i = 0; i < 4; ++i) {
      ah[i] = frag_load(Ah, wr * 64 + i * 16 + lr, g);
      bh[i] = frag_load(Bh, wc * 64 + i * 16 + lr, g);
    }
#pragma unroll
    for (int i = 0; i < 4; ++i)
#pragma unroll
      for (int j = 0; j < 4; ++j)
        acc[i][j] = __builtin_amdgcn_mfma_f32_16x16x32_bf16(ah[i], bh[j], acc[i][j], 0, 0, 0);
    if (SPLIT) {
      bf16x8 al2[4], bl2[4];
#pragma unroll
      for (int i = 0; i < 4; ++i) {
        al2[i] = frag_load(Al, wr * 64 + i * 16 + lr, g);
        bl2[i] = frag_load(Bl, wc * 64 + i * 16 + lr, g);
      }
#pragma unroll
      for (int i = 0; i < 4; ++i)
#pragma unroll
        for (int j = 0; j < 4; ++j)
          acc[i][j] = __builtin_amdgcn_mfma_f32_16x16x32_bf16(al2[i], bh[j], acc[i][j], 0, 0, 0);
#pragma unroll
      for (int i = 0; i < 4; ++i)
#pragma unroll
        for (int j = 0; j < 4; ++j)
          acc[i][j] = __builtin_amdgcn_mfma_f32_16x16x32_bf16(ah[i], bl2[j], acc[i][j], 0, 0, 0);
    }
    __syncthreads();
  }

#pragma unroll
  for (int j = 0; j < 4; ++j) {
    int n = bn + wc * 64 + j * 16 + lr;
    float bj = 0.f;
    if (n < N) {
      if (bias) bj += bias[n];
      if (bias2) bj += bias2[n];
    }
#pragma unroll
    for (int i = 0; i < 4; ++i) {
#pragma unroll
      for (int rr = 0; rr < 4; ++rr) {
        int m = bm + wr * 64 + i * 16 + g * 4 + rr;
        float v = acc[i][j][rr] + bj;
        if (MODE == 0) {
          if (OB)
            ((ushort_t*)Cv)[(long long)m * ldc + n] = (ushort_t)f2bf_u(v);
          else
            ((float*)Cv)[(long long)m * ldc + n] = v;
        } else {
          if (n < N) {
            int b = m & 127, t = m >> 7;
            ((float*)Cv)[(long long)b * (T_ * V_) + (long long)t * V_ + n] =
                (t < declen[b]) ? v : 0.f;
          }
        }
      }
    }
  }
}

// ---------------------------------------------------------------------------
// 64x64 split-bf16 MFMA tile (device helper for the persistent loop kernel)
// ---------------------------------------------------------------------------
__device__ __forceinline__ void mfma_tile64(
    const float* __restrict__ ap, const float* __restrict__ bp, int K,
    f32x4 (&acc)[2][2], short* Ah, short* Al, short* Bh, short* Bl,
    int sr, int skq, int wr, int wc, int lr, int g) {
  float4 a0 = *(const float4*)(ap), a1 = *(const float4*)(ap + 4);
  float4 b0 = *(const float4*)(bp), b1 = *(const float4*)(bp + 4);
  for (int k0 = 0; k0 < K; k0 += 32) {
    stage8(Ah, Al, sr, skq, a0, a1);
    stage8(Bh, Bl, sr, skq, b0, b1);
    __syncthreads();
    if (k0 + 32 < K) {
      a0 = *(const float4*)(ap + k0 + 32);
      a1 = *(const float4*)(ap + k0 + 36);
      b0 = *(const float4*)(bp + k0 + 32);
      b1 = *(const float4*)(bp + k0 + 36);
    }
    bf16x8 fah[2], fbh[2], fal[2], fbl[2];
#pragma unroll
    for (int i = 0; i < 2; ++i) {
      fah[i] = frag_load(Ah, wr * 32 + i * 16 + lr, g);
      fal[i] = frag_load(Al, wr * 32 + i * 16 + lr, g);
      fbh[i] = frag_load(Bh, wc * 32 + i * 16 + lr, g);
      fbl[i] = frag_load(Bl, wc * 32 + i * 16 + lr, g);
    }
#pragma unroll
    for (int i = 0; i < 2; ++i)
#pragma unroll
      for (int j = 0; j < 2; ++j) {
        acc[i][j] = __builtin_amdgcn_mfma_f32_16x16x32_bf16(fah[i], fbh[j], acc[i][j], 0, 0, 0);
        acc[i][j] = __builtin_amdgcn_mfma_f32_16x16x32_bf16(fal[i], fbh[j], acc[i][j], 0, 0, 0);
        acc[i][j] = __builtin_amdgcn_mfma_f32_16x16x32_bf16(fah[i], fbl[j], acc[i][j], 0, 0, 0);
      }
    __syncthreads();
  }
}

// ---------------------------------------------------------------------------
// one-hop software grid barrier
// ---------------------------------------------------------------------------
__device__ __forceinline__ void gsync(unsigned* __restrict__ slots, unsigned target) {
  __syncthreads();
  if (threadIdx.x == 0) {
    __threadfence();
    __hip_atomic_store(&slots[blockIdx.x * 16], target, __ATOMIC_RELEASE,
                       __HIP_MEMORY_SCOPE_AGENT);
  }
  if (threadIdx.x < 64) {
#pragma unroll
    for (int k = 0; k < 4; ++k) {
      unsigned idx = ((unsigned)threadIdx.x * 4 + k) * 16;
      while (__hip_atomic_load(&slots[idx], __ATOMIC_ACQUIRE, __HIP_MEMORY_SCOPE_AGENT) <
             target) {
        __builtin_amdgcn_s_sleep(2);
      }
    }
    __threadfence();
  }
  __syncthreads();
}

// ---------------------------------------------------------------------------
// persistent kernel: the whole 20-step decoder loop, 256 blocks x 256 threads
// ENCBF: att1/enc read as bf16; phase-B streams use deep register prefetch
// ---------------------------------------------------------------------------
template <bool ENCBF>
__global__ __launch_bounds__(256, 1) void loop_kernel(
    const float* __restrict__ att1f, const ushort_t* __restrict__ att1b,
    const float* __restrict__ encf, const ushort_t* __restrict__ encb,
    const int* __restrict__ order, const int* __restrict__ declen,
    const float* __restrict__ decT, const float* __restrict__ decb,
    const float* __restrict__ fbT, const float* __restrict__ fbb,
    const float* __restrict__ whh, const float* __restrict__ wih,
    const float* __restrict__ faw, const float* __restrict__ fab,
    const float* __restrict__ g_all, float* __restrict__ g_part,
    float* __restrict__ gh, float* __restrict__ h_all, float* __restrict__ c,
    float* __restrict__ xh, float* __restrict__ gate, float* __restrict__ att2,
    float* __restrict__ alphas_out, unsigned* __restrict__ bar) {
  __shared__ short Ah[64 * 32];
  __shared__ short Bh[64 * 32];
  __shared__ short Al[64 * 32];
  __shared__ short Bl[64 * 32];
  __shared__ float att2_s[512];
  __shared__ float w_s[512];
  __shared__ float e_s[P_];
  __shared__ float red[8];

  unsigned* slots = bar;
  unsigned tgt = 0;

  const int bid = blockIdx.x, tid = threadIdx.x;
  const int lane = tid & 63, wv = tid >> 6, wr = wv >> 1, wc = wv & 1;
  const int lr = lane & 15, g = lane >> 4;
  const int sr = tid >> 2, skq = tid & 3;

  const float fb0 = fab[0];
  float wr8[8];
  if (ENCBF) {
    const float4* wp = (const float4*)(faw + lane * 8);
#pragma unroll
    for (int q = 0; q < 2; ++q) {
      float4 v = wp[q];
      wr8[q * 4 + 0] = v.x;
      wr8[q * 4 + 1] = v.y;
      wr8[q * 4 + 2] = v.z;
      wr8[q * 4 + 3] = v.w;
    }
  }

  for (int t = 0; t < T_; ++t) {
    const float* h_cur = h_all + t * (B_ * D_);
    // ---------------- phase A ----------------
    if (bid < 144) {
      int nt = bid % 72, mt = bid / 72;
      int bn = nt * 64;
      const float* Bb;
      if (bn < 512) Bb = decT + bn * 512;
      else if (bn < 2560) Bb = fbT + (bn - 512) * 512;
      else Bb = whh + (bn - 2560) * 512;
      f32x4 acc[2][2];
#pragma unroll
      for (int i = 0; i < 2; ++i)
#pragma unroll
        for (int j = 0; j < 2; ++j) acc[i][j] = (f32x4){0.f, 0.f, 0.f, 0.f};
      mfma_tile64(h_cur + (mt * 64 + sr) * 512 + skq * 8, Bb + sr * 512 + skq * 8, 512,
                  acc, Ah, Al, Bh, Bl, sr, skq, wr, wc, lr, g);
#pragma unroll
      for (int j = 0; j < 2; ++j) {
        int n = bn + wc * 32 + j * 16 + lr;
#pragma unroll
        for (int i = 0; i < 2; ++i) {
#pragma unroll
          for (int rr = 0; rr < 4; ++rr) {
            int m = mt * 64 + wr * 32 + i * 16 + g * 4 + rr;
            float v = acc[i][j][rr];
            if (bn < 512) {
              att2[m * 512 + n] = v + decb[n];
            } else if (bn < 2560) {
              int nc = n - 512;
              gate[m * 2048 + nc] = 1.f / (1.f + __expf(-(v + fbb[nc])));
            } else {
              gh[m * 2048 + (n - 2560)] = v;
            }
          }
        }
      }
    }
    gsync(slots, ++tgt);
    // ---------------- phase B ----------------
    {
      const int b = bid & 127, half = bid >> 7;
      if (ENCBF) {
        // e-comp: 4 p-rows per wave-iteration, 4 independent 16B loads
        float a2r[8];
        const float4* a2p = (const float4*)(att2 + b * 512 + lane * 8);
#pragma unroll
        for (int q = 0; q < 2; ++q) {
          float4 v = a2p[q];
          a2r[q * 4 + 0] = v.x;
          a2r[q * 4 + 1] = v.y;
          a2r[q * 4 + 2] = v.z;
          a2r[q * 4 + 3] = v.w;
        }
        const ushort_t* a1base = att1b + (long long)b * P_ * 512 + lane * 8;
        const bf16x8 zv = (bf16x8)(short)0;
        for (int p0 = wv; p0 < P_; p0 += 16) {
          int pA = p0, pB = p0 + 4, pC = p0 + 8, pD = p0 + 12;
          bf16x8 hA = (pA < P_) ? *(const bf16x8*)(a1base + (long long)pA * 512) : zv;
          bf16x8 hB = (pB < P_) ? *(const bf16x8*)(a1base + (long long)pB * 512) : zv;
          bf16x8 hC = (pC < P_) ? *(const bf16x8*)(a1base + (long long)pC * 512) : zv;
          bf16x8 hD = (pD < P_) ? *(const bf16x8*)(a1base + (long long)pD * 512) : zv;
          float sA = 0.f, sB = 0.f, sC = 0.f, sD = 0.f;
#pragma unroll
          for (int j = 0; j < 8; ++j) {
            float xA = bf2f((ushort_t)hA[j]) + a2r[j];
            float xB = bf2f((ushort_t)hB[j]) + a2r[j];
            float xC = bf2f((ushort_t)hC[j]) + a2r[j];
            float xD = bf2f((ushort_t)hD[j]) + a2r[j];
            sA += (xA > 0.f ? xA : 0.f) * wr8[j];
            sB += (xB > 0.f ? xB : 0.f) * wr8[j];
            sC += (xC > 0.f ? xC : 0.f) * wr8[j];
            sD += (xD > 0.f ? xD : 0.f) * wr8[j];
          }
#pragma unroll
          for (int off = 32; off; off >>= 1) {
            sA += __shfl_down(sA, off);
            sB += __shfl_down(sB, off);
            sC += __shfl_down(sC, off);
            sD += __shfl_down(sD, off);
          }
          if (lane == 0) {
            e_s[pA] = sA + fb0;
            if (pB < P_) e_s[pB] = sB + fb0;
            if (pC < P_) e_s[pC] = sC + fb0;
            if (pD < P_) e_s[pD] = sD + fb0;
          }
        }
      } else {
        for (int i = tid; i < 512; i += 256) {
          att2_s[i] = att2[b * 512 + i];
          w_s[i] = faw[i];
        }
        __syncthreads();
        for (int p = wv; p < P_; p += 4) {
          const float* row = att1f + ((long long)b * P_ + p) * 512;
          float s = 0.f;
#pragma unroll
          for (int i2 = 0; i2 < 8; ++i2) {
            int ix = lane + i2 * 64;
            float v = row[ix] + att2_s[ix];
            s += (v > 0.f ? v : 0.f) * w_s[ix];
          }
          for (int off = 32; off; off >>= 1) s += __shfl_down(s, off);
          if (lane == 0) e_s[p] = s + fb0;
        }
      }
      __syncthreads();
      float mx = -1e30f;
      for (int p = tid; p < P_; p += 256) mx = fmaxf(mx, e_s[p]);
      for (int off = 32; off; off >>= 1) mx = fmaxf(mx, __shfl_down(mx, off));
      if (lane == 0) red[wv] = mx;
      __syncthreads();
      mx = fmaxf(fmaxf(red[0], red[1]), fmaxf(red[2], red[3]));
      float ssum = 0.f;
      for (int p = tid; p < P_; p += 256) {
        float ev = __expf(e_s[p] - mx);
        e_s[p] = ev;
        ssum += ev;
      }
      for (int off = 32; off; off >>= 1) ssum += __shfl_down(ssum, off);
      if (lane == 0) red[4 + wv] = ssum;
      __syncthreads();
      float inv = 1.f / (red[4] + red[5] + red[6] + red[7]);
      const bool active = (t < declen[b]);
      for (int p = tid; p < P_; p += 256) {
        float al = e_s[p] * inv;
        e_s[p] = al;
        if (half == 0)
          alphas_out[(long long)b * (T_ * P_) + t * P_ + p] = active ? al : 0.f;
      }
      __syncthreads();
      if (ENCBF) {
        // awe: two-stage software pipeline, 8 independent short4 loads in flight
        const ushort_t* ebc = encb + (long long)b * (P_ * E_) + half * 1024 + tid * 4;
        int col = half * 1024 + tid * 4;
        float s0 = 0.f, s1 = 0.f, s2 = 0.f, s3 = 0.f;
        short4 buf0, buf1, buf2, buf3, buf4, buf5, buf6, buf7;
        buf0 = *(const short4*)(ebc + 0LL * E_);
        buf1 = *(const short4*)(ebc + 1LL * E_);
        buf2 = *(const short4*)(ebc + 2LL * E_);
        buf3 = *(const short4*)(ebc + 3LL * E_);
        buf4 = *(const short4*)(ebc + 4LL * E_);
        buf5 = *(const short4*)(ebc + 5LL * E_);
        buf6 = *(const short4*)(ebc + 6LL * E_);
        buf7 = *(const short4*)(ebc + 7LL * E_);
        for (int p0 = 0; p0 < 184; p0 += 8) {
          short4 c0 = buf0, c1 = buf1, c2 = buf2, c3 = buf3;
          short4 c4 = buf4, c5 = buf5, c6 = buf6, c7 = buf7;
          const ushort_t* nb = ebc + (long long)(p0 + 8) * E_;
          buf0 = *(const short4*)(nb + 0LL * E_);
          buf1 = *(const short4*)(nb + 1LL * E_);
          buf2 = *(const short4*)(nb + 2LL * E_);
          buf3 = *(const short4*)(nb + 3LL * E_);
          buf4 = *(const short4*)(nb + 4LL * E_);
          buf5 = *(const short4*)(nb + 5LL * E_);
          buf6 = *(const short4*)(nb + 6LL * E_);
          buf7 = *(const short4*)(nb + 7LL * E_);
          float a;
          a = e_s[p0 + 0]; s0 += a * bf2f((ushort_t)c0.x); s1 += a * bf2f((ushort_t)c0.y); s2 += a * bf2f((ushort_t)c0.z); s3 += a * bf2f((ushort_t)c0.w);
          a = e_s[p0 + 1]; s0 += a * bf2f((ushort_t)c1.x); s1 += a * bf2f((ushort_t)c1.y); s2 += a * bf2f((ushort_t)c1.z); s3 += a * bf2f((ushort_t)c1.w);
          a = e_s[p0 + 2]; s0 += a * bf2f((ushort_t)c2.x); s1 += a * bf2f((ushort_t)c2.y); s2 += a * bf2f((ushort_t)c2.z); s3 += a * bf2f((ushort_t)c2.w);
          a = e_s[p0 + 3]; s0 += a * bf2f((ushort_t)c3.x); s1 += a * bf2f((ushort_t)c3.y); s2 += a * bf2f((ushort_t)c3.z); s3 += a * bf2f((ushort_t)c3.w);
          a = e_s[p0 + 4]; s0 += a * bf2f((ushort_t)c4.x); s1 += a * bf2f((ushort_t)c4.y); s2 += a * bf2f((ushort_t)c4.z); s3 += a * bf2f((ushort_t)c4.w);
          a = e_s[p0 + 5]; s0 += a * bf2f((ushort_t)c5.x); s1 += a * bf2f((ushort_t)c5.y); s2 += a * bf2f((ushort_t)c5.z); s3 += a * bf2f((ushort_t)c5.w);
          a = e_s[p0 + 6]; s0 += a * bf2f((ushort_t)c6.x); s1 += a * bf2f((ushort_t)c6.y); s2 += a * bf2f((ushort_t)c6.z); s3 += a * bf2f((ushort_t)c6.w);
          a = e_s[p0 + 7]; s0 += a * bf2f((ushort_t)c7.x); s1 += a * bf2f((ushort_t)c7.y); s2 += a * bf2f((ushort_t)c7.z); s3 += a * bf2f((ushort_t)c7.w);
        }
        {
          float a;
          a = e_s[184]; s0 += a * bf2f((ushort_t)buf0.x); s1 += a * bf2f((ushort_t)buf0.y); s2 += a * bf2f((ushort_t)buf0.z); s3 += a * bf2f((ushort_t)buf0.w);
          a = e_s[185]; s0 += a * bf2f((ushort_t)buf1.x); s1 += a * bf2f((ushort_t)buf1.y); s2 += a * bf2f((ushort_t)buf1.z); s3 += a * bf2f((ushort_t)buf1.w);
          a = e_s[186]; s0 += a * bf2f((ushort_t)buf2.x); s1 += a * bf2f((ushort_t)buf2.y); s2 += a * bf2f((ushort_t)buf2.z); s3 += a * bf2f((ushort_t)buf2.w);
          a = e_s[187]; s0 += a * bf2f((ushort_t)buf3.x); s1 += a * bf2f((ushort_t)buf3.y); s2 += a * bf2f((ushort_t)buf3.z); s3 += a * bf2f((ushort_t)buf3.w);
          a = e_s[188]; s0 += a * bf2f((ushort_t)buf4.x); s1 += a * bf2f((ushort_t)buf4.y); s2 += a * bf2f((ushort_t)buf4.z); s3 += a * bf2f((ushort_t)buf4.w);
          a = e_s[189]; s0 += a * bf2f((ushort_t)buf5.x); s1 += a * bf2f((ushort_t)buf5.y); s2 += a * bf2f((ushort_t)buf5.z); s3 += a * bf2f((ushort_t)buf5.w);
          a = e_s[190]; s0 += a * bf2f((ushort_t)buf6.x); s1 += a * bf2f((ushort_t)buf6.y); s2 += a * bf2f((ushort_t)buf6.z); s3 += a * bf2f((ushort_t)buf6.w);
          a = e_s[191]; s0 += a * bf2f((ushort_t)buf7.x); s1 += a * bf2f((ushort_t)buf7.y); s2 += a * bf2f((ushort_t)buf7.z); s3 += a * bf2f((ushort_t)buf7.w);
          short4 t0 = *(const short4*)(ebc + 192LL * E_);
          short4 t1 = *(const short4*)(ebc + 193LL * E_);
          short4 t2 = *(const short4*)(ebc + 194LL * E_);
          short4 t3 = *(const short4*)(ebc + 195LL * E_);
          a = e_s[192]; s0 += a * bf2f((ushort_t)t0.x); s1 += a * bf2f((ushort_t)t0.y); s2 += a * bf2f((ushort_t)t0.z); s3 += a * bf2f((ushort_t)t0.w);
          a = e_s[193]; s0 += a * bf2f((ushort_t)t1.x); s1 += a * bf2f((ushort_t)t1.y); s2 += a * bf2f((ushort_t)t1.z); s3 += a * bf2f((ushort_t)t1.w);
          a = e_s[194]; s0 += a * bf2f((ushort_t)t2.x); s1 += a * bf2f((ushort_t)t2.y); s2 += a * bf2f((ushort_t)t2.z); s3 += a * bf2f((ushort_t)t2.w);
          a = e_s[195]; s0 += a * bf2f((ushort_t)t3.x); s1 += a * bf2f((ushort_t)t3.y); s2 += a * bf2f((ushort_t)t3.z); s3 += a * bf2f((ushort_t)t3.w);
        }
        float4 gv = *(const float4*)(gate + b * 2048 + col);
        float4 o;
        o.x = gv.x * s0;
        o.y = gv.y * s1;
        o.z = gv.z * s2;
        o.w = gv.w * s3;
        *(float4*)(xh + b * 2048 + col) = o;
      } else {
        const int ob = order[b];
        const float* eb = encf + (long long)ob * (P_ * E_);
        for (int e0 = half * 1024 + tid; e0 < half * 1024 + 1024; e0 += 256) {
          float s2 = 0.f;
#pragma unroll 4
          for (int p = 0; p < P_; ++p) s2 += e_s[p] * eb[p * 2048 + e0];
          xh[b * 2048 + e0] = gate[b * 2048 + e0] * s2;
        }
      }
    }
    gsync(slots, ++tgt);
    // ---------------- phase C ----------------
    {
      int kc = bid >> 6, rem = bid & 63, mt = rem >> 5, nt = rem & 31;
      int bn = nt * 64;
      f32x4 acc[2][2];
#pragma unroll
      for (int i = 0; i < 2; ++i)
#pragma unroll
        for (int j = 0; j < 2; ++j) acc[i][j] = (f32x4){0.f, 0.f, 0.f, 0.f};
      mfma_tile64(xh + (mt * 64 + sr) * 2048 + kc * 512 + skq * 8,
                  wih + (long long)(bn + sr) * 2560 + 512 + kc * 512 + skq * 8, 512,
                  acc, Ah, Al, Bh, Bl, sr, skq, wr, wc, lr, g);
      float* gp = g_part + kc * (128 * 2048);
#pragma unroll
      for (int j = 0; j < 2; ++j) {
        int n = bn + wc * 32 + j * 16 + lr;
#pragma unroll
        for (int i = 0; i < 2; ++i) {
#pragma unroll
          for (int rr = 0; rr < 4; ++rr) {
            int m = mt * 64 + wr * 32 + i * 16 + g * 4 + rr;
            gp[m * 2048 + n] = acc[i][j][rr];
          }
        }
      }
    }
    gsync(slots, ++tgt);
    // ---------------- phase D ----------------
    {
      int idx = bid * 256 + tid;
      int b = idx >> 9, d = idx & 511;
      int base = b * 2048 + d;
      const float* ge = g_all + (long long)t * (128 * 2048);
      float gi = ge[base] + gh[base];
      float gf2 = ge[base + 512] + gh[base + 512];
      float gg2 = ge[base + 1024] + gh[base + 1024];
      float go = ge[base + 1536] + gh[base + 1536];
#pragma unroll
      for (int kc = 0; kc < 4; ++kc) {
        const float* gp = g_part + kc * (128 * 2048) + base;
        gi += gp[0];
        gf2 += gp[512];
        gg2 += gp[1024];
        go += gp[1536];
      }
      float si = 1.f / (1.f + __expf(-gi));
      float sf = 1.f / (1.f + __expf(-gf2));
      float so = 1.f / (1.f + __expf(-go));
      float cn = sf * c[idx] + si * tanhf(gg2);
      float hn = so * tanhf(cn);
      c[idx] = cn;
      h_all[(t + 1) * (B_ * D_) + idx] = hn;
    }
    gsync(slots, ++tgt);
  }
}

// ---------------------------------------------------------------------------
// launch
// ---------------------------------------------------------------------------
extern "C" void kernel_launch(void* const* d_in, const int* in_sizes, int n_in,
                              void* d_out, int out_size, void* d_ws, size_t ws_size,
                              hipStream_t stream) {
  const float* enc       = (const float*)d_in[0];
  const int*   caps      = (const int*)d_in[1];
  const int*   lens      = (const int*)d_in[2];
  const float* emb       = (const float*)d_in[3];
  const float* enc_att_w = (const float*)d_in[4];
  const float* enc_att_b = (const float*)d_in[5];
  const float* dec_att_w = (const float*)d_in[6];
  const float* dec_att_b = (const float*)d_in[7];
  const float* full_att_w = (const float*)d_in[8];
  const float* full_att_b = (const float*)d_in[9];
  const float* init_h_w  = (const float*)d_in[10];
  const float* init_h_b  = (const float*)d_in[11];
  const float* init_c_w  = (const float*)d_in[12];
  const float* init_c_b  = (const float*)d_in[13];
  const float* f_beta_w  = (const float*)d_in[14];
  const float* f_beta_b  = (const float*)d_in[15];
  const float* lstm_w_ih = (const float*)d_in[16];
  const float* lstm_b_ih = (const float*)d_in[17];
  const float* lstm_w_hh = (const float*)d_in[18];
  const float* lstm_b_hh = (const float*)d_in[19];
  const float* fc_w      = (const float*)d_in[20];
  const float* fc_b      = (const float*)d_in[21];

  float* out = (float*)d_out;
  float* alphas_out = out + (long long)B_ * T_ * V_;

  // scratch in the (dead until final fc) preds region of d_out
  float* g_all    = out;                                 // 5.24M floats
  float* g_part   = out + 6 * 1024 * 1024;               // 1.05M
  float* encattwT = out + 8 * 1024 * 1024;               // [512][2048]
  float* decT     = out + 9 * 1024 * 1024 + 512 * 1024;  // [512][512]
  float* fbT      = decT + 512 * 512;                    // [2048][512]
  float* gh       = out + 12 * 1024 * 1024;              // [128][2048]

  // workspace layout (cursor-based; bf path needs ~138 MB, fallback ~64 MB)
  size_t cur = 0;
  char* wsb = (char*)d_ws;
  auto alloc = [&](size_t bytes) {
    size_t off = cur;
    cur = (cur + bytes + 255) & ~(size_t)255;
    return (void*)(wsb + off);
  };
  const size_t ATT1B_BYTES = (size_t)B_ * P_ * A_ * 2;        // 25.7 MB
  const size_t ENCB_BYTES  = (size_t)B_ * P_ * E_ * 2;        // 102.8 MB
  const size_t ATT1F_BYTES = (size_t)B_ * P_ * A_ * 4;        // 51.4 MB
  const size_t REST_BYTES  = (size_t)(B_ * E_ + (T_ + 1) * B_ * D_ + B_ * D_ + B_ * A_ +
                                      B_ * E_ + B_ * E_) * 4 +
                             (2 * B_ + B_ * P_ + T_ * B_ + SLOTS_WORDS + 64) * 4 + 4096;
  const bool bfpath = ws_size >= ATT1B_BYTES + ENCB_BYTES + REST_BYTES + (1u << 20);

  ushort_t* att1b = nullptr;
  ushort_t* encbf = nullptr;
  float* att1f = nullptr;
  if (bfpath) {
    att1b = (ushort_t*)alloc(ATT1B_BYTES);
    encbf = (ushort_t*)alloc(ENCB_BYTES);
  } else {
    att1f = (float*)alloc(ATT1F_BYTES);
  }
  float* mean  = (float*)alloc((size_t)B_ * E_ * 4);
  float* h_all = (float*)alloc((size_t)(T_ + 1) * B_ * D_ * 4);
  float* c     = (float*)alloc((size_t)B_ * D_ * 4);
  float* att2  = (float*)alloc((size_t)B_ * A_ * 4);
  float* gate  = (float*)alloc((size_t)B_ * E_ * 4);
  float* xh    = (float*)alloc((size_t)B_ * E_ * 4);
  int* order   = (int*)alloc(B_ * 4);
  int* declen  = (int*)alloc(B_ * 4);
  int* row_map = (int*)alloc((size_t)B_ * P_ * 4);
  int* tok_rows = (int*)alloc((size_t)T_ * B_ * 4);
  unsigned* bar = (unsigned*)alloc(SLOTS_WORDS * 4);

  // 1. sort + index maps + barrier reset
  hipLaunchKernelGGL(order_kernel, dim3(1), dim3(256), 0, stream, lens, caps, order, declen,
                     row_map, tok_rows, bar);
  // 2. weight transposes ([K,N] -> [N,K])
  hipLaunchKernelGGL(transpose_kernel, dim3(16, 64), dim3(256), 0, stream, enc_att_w,
                     encattwT, E_, A_);
  hipLaunchKernelGGL(transpose_kernel, dim3(16, 16), dim3(256), 0, stream, dec_att_w, decT,
                     D_, A_);
  hipLaunchKernelGGL(transpose_kernel, dim3(64, 16), dim3(256), 0, stream, f_beta_w, fbT,
                     D_, E_);
  // 3. mean
  hipLaunchKernelGGL(mean_kernel, dim3(E_ / 256, B_), dim3(256), 0, stream, enc, order, mean);
  // 4/5. h0, c0 (fp32)
  hipLaunchKernelGGL(gemm32_kernel, dim3(D_ / 64, 2), dim3(256), 0, stream, mean, init_h_w,
                     init_h_b, h_all, B_, D_, E_);
  hipLaunchKernelGGL(gemm32_kernel, dim3(D_ / 64, 2), dim3(256), 0, stream, mean, init_c_w,
                     init_c_b, c, B_, D_, E_);
  // 6. att1 (plain bf16 MFMA; bf path emits bf16 output)
  if (bfpath) {
    hipLaunchKernelGGL((mfma_gemm<0, false, true, true>), dim3(A_ / 128, (B_ * P_) / 128),
                       dim3(256), 0, stream, enc, E_, row_map, encattwT, E_, enc_att_b,
                       (const float*)nullptr, (void*)att1b, A_, B_ * P_, A_, E_,
                       (const int*)nullptr);
    hipLaunchKernelGGL(enc2bf_kernel, dim3(B_ * P_), dim3(256), 0, stream, enc, row_map,
                       encbf);
  } else {
    hipLaunchKernelGGL((mfma_gemm<0, false, true, false>), dim3(A_ / 128, (B_ * P_) / 128),
                       dim3(256), 0, stream, enc, E_, row_map, encattwT, E_, enc_att_b,
                       (const float*)nullptr, (void*)att1f, A_, B_ * P_, A_, E_,
                       (const int*)nullptr);
  }
  // 7. g_all = emb(tok) @ W_ih[:, :512]^T + b_ih + b_hh   (split bf16 MFMA)
  hipLaunchKernelGGL((mfma_gemm<0, true, false, false>), dim3((4 * D_) / 128, (T_ * B_) / 128),
                     dim3(256), 0, stream, emb, M_, tok_rows, lstm_w_ih, M_ + E_, lstm_b_ih,
                     lstm_b_hh, (void*)g_all, 4 * D_, T_ * B_, 4 * D_, M_,
                     (const int*)nullptr);
  // 8. the decode loop: one persistent kernel with one-hop slot barrier
  if (bfpath) {
    hipLaunchKernelGGL((loop_kernel<true>), dim3(NBLK_), dim3(256), 0, stream,
                       (const float*)nullptr, att1b, (const float*)nullptr, encbf, order,
                       declen, decT, dec_att_b, fbT, f_beta_b, lstm_w_hh, lstm_w_ih,
                       full_att_w, full_att_b, g_all, g_part, gh, h_all, c, xh, gate, att2,
                       alphas_out, bar);
  } else {
    hipLaunchKernelGGL((loop_kernel<false>), dim3(NBLK_), dim3(256), 0, stream, att1f,
                       (const ushort_t*)nullptr, enc, (const ushort_t*)nullptr, order,
                       declen, decT, dec_att_b, fbT, f_beta_b, lstm_w_hh, lstm_w_ih,
                       full_att_w, full_att_b, g_all, g_part, gh, h_all, c, xh, gate, att2,
                       alphas_out, bar);
  }
  // 9. batched fc over all (t,b), masked scatter (split bf16 MFMA)
  hipLaunchKernelGGL((mfma_gemm<1, true, false, false>), dim3((V_ + 127) / 128,
                     (T_ * B_) / 128), dim3(256), 0, stream, h_all + B_ * D_, D_,
                     (const int*)nullptr, fc_w, D_, fc_b, (const float*)nullptr, (void*)out,
                     V_, T_ * B_, V_, D_, declen);
}